// Round 1
// baseline (1243.542 us; speedup 1.0000x reference)
//
#include <hip/hip_runtime.h>
#include <hip/hip_bf16.h>

#define BS 4
#define LL 1024
#define DD 768
#define HH 12
#define NE 42
#define NM 8
#define KK 97
#define PPAIR 128
#define FF 256
#define RR 256
#define NPAIR (BS*PPAIR)     // 512
#define MROWS (BS*NE*KK)     // 16296
#define MT 510               // ceil(16296/32)
#define GRID_BIL 832         // 8 xcd * 8 ntile * ceil(KK/8)=13

typedef __attribute__((ext_vector_type(8))) short short8;
typedef __attribute__((ext_vector_type(16))) float float16;

__device__ __forceinline__ float fast_tanh(float x){
  x = fminf(fmaxf(x, -15.f), 15.f);
  float e = __expf(2.f*x);
  return 1.f - 2.f/(e + 1.f);
}
__device__ __forceinline__ unsigned short f2bf(float f){
  unsigned int u = __float_as_uint(f);
  unsigned int r = (u + 0x7FFF + ((u>>16)&1)) >> 16;
  return (unsigned short)r;
}
__device__ __forceinline__ float bf2f(unsigned short u){
  return __uint_as_float(((unsigned int)u)<<16);
}

// ---------------- K1: emb[b,e,m,:] = seq[b,pos,:] * mask ----------------
__global__ void k_emb(const float* __restrict__ seq, const int* __restrict__ mpos,
                      const float* __restrict__ mask, float* __restrict__ emb){
  int idx = blockIdx.x;            // (b*NE+e)*NM+m
  int t = threadIdx.x;
  int b = idx / (NE*NM);
  float mk = mask[idx];
  int pos = mpos[idx] + 1;
  pos = min(max(pos, 0), LL-1);
  const float* src = seq + ((size_t)b*LL + pos)*DD;
  float* dst = emb + (size_t)idx*DD;
  for (int dd = t; dd < DD; dd += 256) dst[dd] = mk * src[dd];
}

// ------------- K2: entity_as[b,e,h,l] = sum_m mask*att[b,h,pos,l]/cnt -------------
__global__ void k_entity_as(const float* __restrict__ att, const int* __restrict__ mpos,
                            const float* __restrict__ mask, float* __restrict__ eas){
  int idx = blockIdx.x;            // (b*NE+e)*HH + hh
  int hh = idx % HH; int be = idx / HH;
  int b = be / NE;
  int t = threadIdx.x;
  float cnt = 0.f;
  for (int m=0;m<NM;m++) cnt += mask[be*NM+m];
  float inv = 1.f / fmaxf(cnt, 1.f);
  float acc[4] = {0.f,0.f,0.f,0.f};
  for (int m=0;m<NM;m++){
    float mk = mask[be*NM+m];
    if (mk != 0.f){
      int pos = min(max(mpos[be*NM+m]+1,0), LL-1);
      const float* row = att + (((size_t)b*HH + hh)*LL + pos)*LL;
      acc[0] += mk*row[t]; acc[1] += mk*row[t+256];
      acc[2] += mk*row[t+512]; acc[3] += mk*row[t+768];
    }
  }
  float* dst = eas + (size_t)idx*LL;
  dst[t]=acc[0]*inv; dst[t+256]=acc[1]*inv; dst[t+512]=acc[2]*inv; dst[t+768]=acc[3]*inv;
}

// ------------- K3a: tbuf[b,e,m,r] = tanh(emb . Wattn[:,r] + battn[r]) -------------
__global__ void k_score1(const float* __restrict__ emb, const float* __restrict__ Wattn,
                         const float* __restrict__ battn, float* __restrict__ tbuf){
  int idx = blockIdx.x; int t = threadIdx.x;  // 256 threads, r = t
  __shared__ float es[DD];
  es[t]       = emb[(size_t)idx*DD + t];
  es[t+256]   = emb[(size_t)idx*DD + t + 256];
  es[t+512]   = emb[(size_t)idx*DD + t + 512];
  __syncthreads();
  float acc = battn[t];
  for (int dd=0; dd<DD; dd++) acc += es[dd]*Wattn[dd*RR + t];
  tbuf[(size_t)idx*RR + t] = fast_tanh(acc);
}

// ------------- K3b: scores + masked softmax over mentions -> w[b,e,m,k] -------------
__global__ void k_scores(const float* __restrict__ tbuf, const float* __restrict__ an,
                         const float* __restrict__ mask, float* __restrict__ w){
  int be = blockIdx.x; int t = threadIdx.x;   // 128 threads
  __shared__ float ts_[NM*RR];                // 8 KB
  __shared__ float an_s[64*98];               // 25 KB chunk of attn_net^T
  for (int i=t; i<NM*RR; i+=128) ts_[i] = tbuf[(size_t)be*NM*RR + i];
  float acc[NM];
  #pragma unroll
  for (int m=0;m<NM;m++) acc[m] = 0.f;
  for (int rc=0; rc<RR; rc+=64){
    __syncthreads();
    for (int i=t; i<KK*64; i+=128){
      int kq = i >> 6, r = i & 63;
      an_s[r*98 + kq] = an[kq*RR + rc + r];
    }
    __syncthreads();
    if (t < KK){
      for (int m=0;m<NM;m++){
        float a = 0.f;
        for (int r=0;r<64;r++) a += ts_[m*RR + rc + r]*an_s[r*98 + t];
        acc[m] += a;
      }
    }
  }
  if (t < KK){
    float s[NM];
    #pragma unroll
    for (int m=0;m<NM;m++){
      float mk = mask[be*NM+m];
      s[m] = acc[m] + (1.f - mk)*(-1e6f);
    }
    float mx = s[0];
    #pragma unroll
    for (int m=1;m<NM;m++) mx = fmaxf(mx, s[m]);
    float sum = 0.f; float e[NM];
    #pragma unroll
    for (int m=0;m<NM;m++){ e[m] = __expf(s[m]-mx); sum += e[m]; }
    float invs = 1.f/sum;
    #pragma unroll
    for (int m=0;m<NM;m++) w[((size_t)be*NM+m)*KK + t] = e[m]*invs;
  }
}

// ------- K4: entity_es -> bf16 in A-fragment order for 32x32x16 MFMA -------
// es_frag[mt][ds][lane][8]: lane = (row&31) + 32*((d>>3)&1), j = d&7, ds = d>>4
__global__ void k_entity_es(const float* __restrict__ emb, const float* __restrict__ w,
                            unsigned short* __restrict__ esf){
  int be = blockIdx.x; int t = threadIdx.x;
  __shared__ float es[NM*DD];    // 24 KB
  __shared__ float ws_[NM*KK];
  for (int i = t; i < NM*DD; i += 256) es[i] = emb[(size_t)be*NM*DD + i];
  for (int i = t; i < NM*KK; i += 256) ws_[i] = w[(size_t)be*NM*KK + i];
  __syncthreads();
  for (int idx = t; idx < KK*96; idx += 256){
    int k = idx % KK, d8 = idx / KK;     // lanes consecutive in k -> broadcast es reads
    int d0 = d8*8;
    float a[8] = {0,0,0,0,0,0,0,0};
    #pragma unroll
    for (int m=0;m<NM;m++){
      float wv = ws_[m*KK + k];
      #pragma unroll
      for (int j=0;j<8;j++) a[j] += wv*es[m*DD + d0 + j];
    }
    int row = be*KK + k;
    int mt = row >> 5, lr = row & 31, ds = d8 >> 1, qq = d8 & 1;
    short8 v;
    #pragma unroll
    for (int j=0;j<8;j++) v[j] = (short)f2bf(a[j]);
    *(short8*)(esf + ((((size_t)mt*48) + ds)*64 + lr + 32*qq)*8) = v;
  }
}

// ------------- K6: seqlin[b,l,c] = seq[b,l,:] . Wlin[:,c] -------------
__global__ void k_seqlin(const float* __restrict__ seq, const float* __restrict__ Wlin,
                         float* __restrict__ sl){
  int bl = blockIdx.x; int t = threadIdx.x;
  const float* row = seq + (size_t)bl*DD;
  float a[3] = {0.f,0.f,0.f};
  for (int dd=t; dd<DD; dd+=256){
    float v = row[dd];
    a[0] += v*Wlin[dd*3+0]; a[1] += v*Wlin[dd*3+1]; a[2] += v*Wlin[dd*3+2];
  }
  __shared__ float red[256];
  float res[3];
  for (int c=0;c<3;c++){
    red[t] = a[c]; __syncthreads();
    for (int off=128; off>0; off>>=1){ if (t<off) red[t]+=red[t+off]; __syncthreads(); }
    res[c] = red[0]; __syncthreads();
  }
  if (t==0){ sl[bl*3+0]=res[0]; sl[bl*3+1]=res[1]; sl[bl*3+2]=res[2]; }
}

// ------------- K5: fused ht einsum + row-normalize + x = htn@seqlin + blin -------------
// Rewritten: wave-level __shfl_xor butterfly reductions (2 barriers instead of ~36)
__global__ void k_ht_x(const float* __restrict__ eas, const float* __restrict__ sl,
                       const float* __restrict__ blin, float* __restrict__ x){
  int idx = blockIdx.x;            // (b*NE+i)*NE + j
  int j = idx % NE; int i = (idx/NE)%NE; int b = idx/(NE*NE);
  int t = threadIdx.x;
  int w = t >> 6, lane = t & 63;
  const float* ai = eas + ((size_t)(b*NE+i))*HH*LL;
  const float* aj = eas + ((size_t)(b*NE+j))*HH*LL;
  float v[4];
  #pragma unroll
  for (int it=0; it<4; it++){
    int l = t + it*256;
    float acc=0.f;
    #pragma unroll
    for (int hh2=0; hh2<HH; hh2++) acc += ai[hh2*LL + l]*aj[hh2*LL + l];
    v[it] = acc * (1.f/HH);
  }
  __shared__ float wsum[4];
  __shared__ float xred[4][3];
  float s = v[0]+v[1]+v[2]+v[3];
  s += __shfl_xor(s, 1);  s += __shfl_xor(s, 2);  s += __shfl_xor(s, 4);
  s += __shfl_xor(s, 8);  s += __shfl_xor(s, 16); s += __shfl_xor(s, 32);
  if (lane == 0) wsum[w] = s;
  __syncthreads();
  float inv = 1.f/((wsum[0]+wsum[1]+wsum[2]+wsum[3]) + 1e-5f);
  float xa[3]={0.f,0.f,0.f};
  #pragma unroll
  for (int it=0; it<4; it++){
    int l = t + it*256;
    float wv = v[it]*inv;
    const float* s3 = sl + ((size_t)b*LL + l)*3;
    xa[0]+=wv*s3[0]; xa[1]+=wv*s3[1]; xa[2]+=wv*s3[2];
  }
  #pragma unroll
  for (int c=0;c<3;c++){
    float q = xa[c];
    q += __shfl_xor(q, 1);  q += __shfl_xor(q, 2);  q += __shfl_xor(q, 4);
    q += __shfl_xor(q, 8);  q += __shfl_xor(q, 16); q += __shfl_xor(q, 32);
    if (lane == 0) xred[w][c] = q;
  }
  __syncthreads();
  if (t < 3) x[(size_t)idx*3 + t] = xred[0][t]+xred[1][t]+xred[2][t]+xred[3][t] + blin[t];
}

// ------------- K8: 3x3x(3->256) conv + relu at gathered pairs -------------
__global__ void k_conv_pairs(const float* __restrict__ x, const int* __restrict__ pairs,
                             const float* __restrict__ Wseg, const float* __restrict__ bseg,
                             float* __restrict__ htss){
  int n = blockIdx.x; int t = threadIdx.x;   // t = f channel
  int b = n / PPAIR;
  int hi = pairs[n*2+0], ti = pairs[n*2+1];
  __shared__ float xs[27];
  if (t < 27){
    int di = t/9, dj = (t/3)%3, ci = t%3;
    int ii = hi + di - 1, jj = ti + dj - 1;
    float v = 0.f;
    if (ii>=0 && ii<NE && jj>=0 && jj<NE) v = x[(((size_t)b*NE+ii)*NE+jj)*3 + ci];
    xs[t] = v;
  }
  __syncthreads();
  float acc = bseg[t];
  #pragma unroll
  for (int tap=0; tap<27; tap++) acc += xs[tap]*Wseg[tap*FF + t];
  htss[(size_t)n*FF + t] = fmaxf(acc, 0.f);
}

// ------------- K9: pairh[n,:] = htss[n,:] @ W[768:1024,:] + bias -------------
__global__ void k_pair_proj(const float* __restrict__ htss, const float* __restrict__ Wb,
                            const float* __restrict__ bias, float* __restrict__ outp){
  int n = blockIdx.x; int t = threadIdx.x;
  __shared__ float hs_s[FF];
  hs_s[t] = htss[(size_t)n*FF + t];
  __syncthreads();
  float a0 = bias[t], a1 = bias[t+256], a2 = bias[t+512];
  for (int r=0;r<FF;r++){
    float hv = hs_s[r];
    const float* wr = Wb + (size_t)r*DD;
    a0 += hv*wr[t]; a1 += hv*wr[t+256]; a2 += hv*wr[t+512];
  }
  float* dst = outp + (size_t)n*DD;
  dst[t]=a0; dst[t+256]=a1; dst[t+512]=a2;
}

// ------- K-shuffle: fp32 [768(k)][768(n)] -> bf16 B-frag order -------
// dst[ds(48)][nt(24)][lane(64)][j(8)]: lane = (n&31)+32*((k>>3)&1), j=k&7
__global__ void k_wshuffle(const float* __restrict__ src, unsigned short* __restrict__ dst){
  int bi = blockIdx.x;
  int mat = bi / 144; int r = bi % 144;
  int ds = r / 3, ntg = r % 3;
  int t = threadIdx.x;
  size_t mo = (size_t)mat*589824;
  __shared__ float ls[16][260];
  #pragma unroll
  for (int i=0;i<16;i++)
    ls[i][t] = src[mo + ((size_t)(ds*16+i))*768 + ntg*256 + t];
  __syncthreads();
  #pragma unroll
  for (int it=0; it<2; it++){
    int idx = it*256 + t;           // 0..511
    int pt_l = idx >> 6, lane = idx & 63;
    int nl = pt_l*32 + (lane & 31);
    int qq = lane >> 5;
    short8 v;
    #pragma unroll
    for (int j=0;j<8;j++) v[j] = (short)f2bf(ls[qq*8 + j][nl]);
    *(short8*)(dst + mo + (((size_t)ds*24 + ntg*8 + pt_l)*64 + lane)*8) = v;
  }
}

// ------------- K10: C_bf16[M,768] = A_frag @ B_frag (32x32x16 MFMA, LDS-free) -------------
__global__ __launch_bounds__(256) void k_gemm_frag(const unsigned short* __restrict__ Af,
    const unsigned short* __restrict__ Bf, unsigned short* __restrict__ C){
  int mt = blockIdx.x / 6, ntg = blockIdx.x % 6;
  int t = threadIdx.x; int w = t >> 6; int lane = t & 63;
  int nt = ntg*4 + w;
  float16 acc = (float16)(0.0f);
  const unsigned short* ap = Af + (((size_t)mt*48)*64 + lane)*8;
  const unsigned short* bp = Bf + (((size_t)nt)*64 + lane)*8;
  #pragma unroll 4
  for (int ds=0; ds<48; ds++){
    short8 a = *(const short8*)(ap + (size_t)ds*512);
    short8 b = *(const short8*)(bp + (size_t)ds*24*512);
    acc = __builtin_amdgcn_mfma_f32_32x32x16_bf16(a, b, acc, 0, 0, 0);
  }
  int col = nt*32 + (lane & 31);
  int aq = lane >> 5;
  #pragma unroll
  for (int rI=0;rI<16;rI++){
    int row = mt*32 + (rI&3) + 8*(rI>>2) + 4*aq;
    C[(size_t)row*768 + col] = f2bf(acc[rI]);
  }
}

// ------------- K11: bilinear via MFMA -------------
// XCD-aligned bijective swizzle: all 8 n-tiles sharing BF[k] land on the SAME XCD
// (blockIdx % 8 == k % 8) so 7 of 8 streams of the 1.18 MB BF[k] matrix hit that
// XCD's 4 MB L2 instead of re-fetching from L3/HBM.
// blockIdx = (k&7) + 8*((k>>3)*8 + ntile); grid = 8*8*13 = 832, k>=97 early-out.
__global__ __launch_bounds__(256,2) void k_bilinear_mfma(
    const unsigned short* __restrict__ Ehb, const unsigned short* __restrict__ Etb,
    const float* __restrict__ ph, const float* __restrict__ pt_,
    const unsigned short* __restrict__ Bfrag, const float* __restrict__ bias,
    const int* __restrict__ pairs, float* __restrict__ out){
  int xcd = blockIdx.x & 7;
  int g   = blockIdx.x >> 3;
  int k   = ((g >> 3) << 3) | xcd;
  if (k >= KK) return;
  int n0 = (g & 7)*64;
  int t = threadIdx.x; int w = t >> 6; int lane = t & 63;
  int wr = w & 1, wc = w >> 1;
  __shared__ int ehB[64], etB[64];
  __shared__ float redbuf[2][2][32];   // [wr][wc][row]
  if (t < 64){
    int n = n0 + t; int b = n >> 7;
    ehB[t] = ((b*NE + pairs[n*2+0])*KK + k)*DD;
    etB[t] = ((b*NE + pairs[n*2+1])*KK + k)*DD;
  }
  __syncthreads();
  int arow = wr*32 + (lane & 31);
  int aq = lane >> 5;
  const unsigned short* ehp = Ehb + ehB[arow];
  const float* php = ph + (size_t)(n0 + arow)*DD;
  const unsigned short* bb = Bfrag + (size_t)k*589824 + (size_t)lane*8;
  float16 acc[12];
  #pragma unroll
  for (int i=0;i<12;i++) acc[i] = (float16)(0.0f);
  for (int ds=0; ds<48; ds++){
    int d0 = ds*16 + aq*8;
    short8 ev = *(const short8*)(ehp + d0);
    float4 p0 = *(const float4*)(php + d0);
    float4 p1 = *(const float4*)(php + d0 + 4);
    float pf[8] = {p0.x,p0.y,p0.z,p0.w,p1.x,p1.y,p1.z,p1.w};
    short8 afrag;
    #pragma unroll
    for (int j=0;j<8;j++)
      afrag[j] = (short)f2bf(fast_tanh(bf2f((unsigned short)ev[j]) + pf[j]));
    const unsigned short* bds = bb + (size_t)ds*24*512;
    #pragma unroll
    for (int p2=0; p2<12; p2++){
      short8 bfr = *(const short8*)(bds + (size_t)(p2*2 + wc)*512);
      acc[p2] = __builtin_amdgcn_mfma_f32_32x32x16_bf16(afrag, bfr, acc[p2], 0, 0, 0);
    }
  }
  // epilogue: s[row] = sum_{p in this wave's half} U[row,p]*tanh(Et+pt)[row,p]
  #pragma unroll
  for (int rI=0;rI<16;rI++){
    int row = (rI&3) + 8*(rI>>2) + 4*aq;      // 0..31 within wave's half
    int nloc = wr*32 + row;
    int eb = etB[nloc];
    const float* ptp = pt_ + (size_t)(n0 + nloc)*DD;
    float s = 0.f;
    #pragma unroll
    for (int p2=0; p2<12; p2++){
      int col = (p2*2 + wc)*32 + (lane & 31);
      float tv = fast_tanh(bf2f(Etb[eb + col]) + ptp[col]);
      s += acc[p2][rI]*tv;
    }
    s += __shfl_xor(s, 1);  s += __shfl_xor(s, 2);
    s += __shfl_xor(s, 4);  s += __shfl_xor(s, 8);
    s += __shfl_xor(s, 16);
    if ((lane & 31) == 0) redbuf[wr][wc][row] = s;
  }
  __syncthreads();
  if (t < 64){
    int wrr = t >> 5, r = t & 31;
    out[(size_t)(n0 + t)*KK + k] = redbuf[wrr][0][r] + redbuf[wrr][1][r] + bias[k];
  }
}

extern "C" void kernel_launch(void* const* d_in, const int* in_sizes, int n_in,
                              void* d_out, int out_size, void* d_ws, size_t ws_size,
                              hipStream_t stream){
  const float* seq      = (const float*)d_in[0];
  const float* att      = (const float*)d_in[1];
  const float* mask     = (const float*)d_in[2];
  const int*   mpos     = (const int*)d_in[3];
  const int*   pairs    = (const int*)d_in[4];
  const float* Wattn    = (const float*)d_in[5];
  const float* battn    = (const float*)d_in[6];
  const float* attn_net = (const float*)d_in[7];
  const float* Wlin     = (const float*)d_in[8];
  const float* blin     = (const float*)d_in[9];
  const float* Wseg     = (const float*)d_in[10];
  const float* bseg     = (const float*)d_in[11];
  const float* Whead    = (const float*)d_in[12];
  const float* bhead    = (const float*)d_in[13];
  const float* Wtail    = (const float*)d_in[14];
  const float* btail    = (const float*)d_in[15];
  const float* bil      = (const float*)d_in[16];
  const float* bilb     = (const float*)d_in[17];
  float* out = (float*)d_out;

  char* ws = (char*)d_ws;
  size_t off = 0;
  auto allocB = [&](size_t nbytes)->char*{
    char* p = ws + off;
    off += (nbytes + 255) & ~(size_t)255;
    return p;
  };
  float* emb  = (float*)allocB((size_t)BS*NE*NM*DD*4);
  float* tbuf = (float*)allocB((size_t)BS*NE*NM*RR*4);
  float* wsm  = (float*)allocB((size_t)BS*NE*NM*KK*4);
  float* eas  = (float*)allocB((size_t)BS*NE*HH*LL*4);
  float* sl   = (float*)allocB((size_t)BS*LL*3*4);
  float* xb   = (float*)allocB((size_t)BS*NE*NE*3*4);
  float* htss = (float*)allocB((size_t)NPAIR*FF*4);
  float* phb  = (float*)allocB((size_t)NPAIR*DD*4);
  float* ptb  = (float*)allocB((size_t)NPAIR*DD*4);
  unsigned short* esf    = (unsigned short*)allocB((size_t)MT*48*64*8*2);   // 25 MB
  unsigned short* WheadF = (unsigned short*)allocB((size_t)589824*2);
  unsigned short* WtailF = (unsigned short*)allocB((size_t)589824*2);
  unsigned short* BF     = (unsigned short*)allocB((size_t)KK*589824*2);    // 114.4 MB
  unsigned short* Ehb    = (unsigned short*)allocB((size_t)MT*32*768*2);    // 25 MB
  unsigned short* Etb    = (unsigned short*)allocB((size_t)MT*32*768*2);    // 25 MB

  k_emb<<<BS*NE*NM, 256, 0, stream>>>(seq, mpos, mask, emb);
  k_score1<<<BS*NE*NM, 256, 0, stream>>>(emb, Wattn, battn, tbuf);
  k_scores<<<BS*NE, 128, 0, stream>>>(tbuf, attn_net, mask, wsm);
  k_entity_as<<<BS*NE*HH, 256, 0, stream>>>(att, mpos, mask, eas);
  k_entity_es<<<BS*NE, 256, 0, stream>>>(emb, wsm, esf);
  k_seqlin<<<BS*LL, 256, 0, stream>>>(seq, Wlin, sl);
  k_ht_x<<<BS*NE*NE, 256, 0, stream>>>(eas, sl, blin, xb);
  k_conv_pairs<<<NPAIR, 256, 0, stream>>>(xb, pairs, Wseg, bseg, htss);
  k_pair_proj<<<NPAIR, 256, 0, stream>>>(htss, Whead + 768*768, bhead, phb);
  k_pair_proj<<<NPAIR, 256, 0, stream>>>(htss, Wtail + 768*768, btail, ptb);
  k_wshuffle<<<144, 256, 0, stream>>>(Whead, WheadF);
  k_wshuffle<<<144, 256, 0, stream>>>(Wtail, WtailF);
  k_wshuffle<<<KK*144, 256, 0, stream>>>(bil, BF);
  k_gemm_frag<<<MT*6, 256, 0, stream>>>(esf, WheadF, Ehb);
  k_gemm_frag<<<MT*6, 256, 0, stream>>>(esf, WtailF, Etb);
  k_bilinear_mfma<<<GRID_BIL, 256, 0, stream>>>(Ehb, Etb, phb, ptb, BF, bilb, pairs, out);
}

// Round 2
// 970.569 us; speedup vs baseline: 1.2813x; 1.2813x over previous
//
#include <hip/hip_runtime.h>
#include <hip/hip_bf16.h>

#define BS 4
#define LL 1024
#define DD 768
#define HH 12
#define NE 42
#define NM 8
#define KK 97
#define PPAIR 128
#define FF 256
#define RR 256
#define NPAIR (BS*PPAIR)     // 512
#define MROWS (BS*NE*KK)     // 16296
#define MT 510               // ceil(16296/32)
#define NT32 16              // 512 pair-rows / 32
#define GRID_BG (8*13*16)    // xcd(8) x kgrp(13) x nt128(4) x ps(4) = 1664

typedef __attribute__((ext_vector_type(8))) short short8;
typedef __attribute__((ext_vector_type(16))) float float16;

__device__ __forceinline__ float fast_tanh(float x){
  x = fminf(fmaxf(x, -15.f), 15.f);
  float e = __expf(2.f*x);
  return 1.f - 2.f/(e + 1.f);
}
__device__ __forceinline__ unsigned short f2bf(float f){
  unsigned int u = __float_as_uint(f);
  unsigned int r = (u + 0x7FFF + ((u>>16)&1)) >> 16;
  return (unsigned short)r;
}
__device__ __forceinline__ float bf2f(unsigned short u){
  return __uint_as_float(((unsigned int)u)<<16);
}

// ---------------- K1: emb[b,e,m,:] = seq[b,pos,:] * mask ----------------
__global__ void k_emb(const float* __restrict__ seq, const int* __restrict__ mpos,
                      const float* __restrict__ mask, float* __restrict__ emb){
  int idx = blockIdx.x;            // (b*NE+e)*NM+m
  int t = threadIdx.x;
  int b = idx / (NE*NM);
  float mk = mask[idx];
  int pos = mpos[idx] + 1;
  pos = min(max(pos, 0), LL-1);
  const float* src = seq + ((size_t)b*LL + pos)*DD;
  float* dst = emb + (size_t)idx*DD;
  for (int dd = t; dd < DD; dd += 256) dst[dd] = mk * src[dd];
}

// ------------- K2: entity_as[b,e,h,l] = sum_m mask*att[b,h,pos,l]/cnt -------------
__global__ void k_entity_as(const float* __restrict__ att, const int* __restrict__ mpos,
                            const float* __restrict__ mask, float* __restrict__ eas){
  int idx = blockIdx.x;            // (b*NE+e)*HH + hh
  int hh = idx % HH; int be = idx / HH;
  int b = be / NE;
  int t = threadIdx.x;
  float cnt = 0.f;
  for (int m=0;m<NM;m++) cnt += mask[be*NM+m];
  float inv = 1.f / fmaxf(cnt, 1.f);
  float acc[4] = {0.f,0.f,0.f,0.f};
  for (int m=0;m<NM;m++){
    float mk = mask[be*NM+m];
    if (mk != 0.f){
      int pos = min(max(mpos[be*NM+m]+1,0), LL-1);
      const float* row = att + (((size_t)b*HH + hh)*LL + pos)*LL;
      acc[0] += mk*row[t]; acc[1] += mk*row[t+256];
      acc[2] += mk*row[t+512]; acc[3] += mk*row[t+768];
    }
  }
  float* dst = eas + (size_t)idx*LL;
  dst[t]=acc[0]*inv; dst[t+256]=acc[1]*inv; dst[t+512]=acc[2]*inv; dst[t+768]=acc[3]*inv;
}

// ------------- K3a: tbuf[b,e,m,r] = tanh(emb . Wattn[:,r] + battn[r]) -------------
__global__ void k_score1(const float* __restrict__ emb, const float* __restrict__ Wattn,
                         const float* __restrict__ battn, float* __restrict__ tbuf){
  int idx = blockIdx.x; int t = threadIdx.x;  // 256 threads, r = t
  __shared__ float es[DD];
  es[t]       = emb[(size_t)idx*DD + t];
  es[t+256]   = emb[(size_t)idx*DD + t + 256];
  es[t+512]   = emb[(size_t)idx*DD + t + 512];
  __syncthreads();
  float acc = battn[t];
  for (int dd=0; dd<DD; dd++) acc += es[dd]*Wattn[dd*RR + t];
  tbuf[(size_t)idx*RR + t] = fast_tanh(acc);
}

// ------------- K3b: scores + masked softmax over mentions -> w[b,e,m,k] -------------
__global__ void k_scores(const float* __restrict__ tbuf, const float* __restrict__ an,
                         const float* __restrict__ mask, float* __restrict__ w){
  int be = blockIdx.x; int t = threadIdx.x;   // 128 threads
  __shared__ float ts_[NM*RR];                // 8 KB
  __shared__ float an_s[64*98];               // 25 KB chunk of attn_net^T
  for (int i=t; i<NM*RR; i+=128) ts_[i] = tbuf[(size_t)be*NM*RR + i];
  float acc[NM];
  #pragma unroll
  for (int m=0;m<NM;m++) acc[m] = 0.f;
  for (int rc=0; rc<RR; rc+=64){
    __syncthreads();
    for (int i=t; i<KK*64; i+=128){
      int kq = i >> 6, r = i & 63;
      an_s[r*98 + kq] = an[kq*RR + rc + r];
    }
    __syncthreads();
    if (t < KK){
      for (int m=0;m<NM;m++){
        float a = 0.f;
        for (int r=0;r<64;r++) a += ts_[m*RR + rc + r]*an_s[r*98 + t];
        acc[m] += a;
      }
    }
  }
  if (t < KK){
    float s[NM];
    #pragma unroll
    for (int m=0;m<NM;m++){
      float mk = mask[be*NM+m];
      s[m] = acc[m] + (1.f - mk)*(-1e6f);
    }
    float mx = s[0];
    #pragma unroll
    for (int m=1;m<NM;m++) mx = fmaxf(mx, s[m]);
    float sum = 0.f; float e[NM];
    #pragma unroll
    for (int m=0;m<NM;m++){ e[m] = __expf(s[m]-mx); sum += e[m]; }
    float invs = 1.f/sum;
    #pragma unroll
    for (int m=0;m<NM;m++) w[((size_t)be*NM+m)*KK + t] = e[m]*invs;
  }
}

// ------- K4: entity_es -> bf16 in A-fragment order for 32x32x16 MFMA -------
// es_frag[mt][ds][lane][8]: lane = (row&31) + 32*((d>>3)&1), j = d&7, ds = d>>4
__global__ void k_entity_es(const float* __restrict__ emb, const float* __restrict__ w,
                            unsigned short* __restrict__ esf){
  int be = blockIdx.x; int t = threadIdx.x;
  __shared__ float es[NM*DD];    // 24 KB
  __shared__ float ws_[NM*KK];
  for (int i = t; i < NM*DD; i += 256) es[i] = emb[(size_t)be*NM*DD + i];
  for (int i = t; i < NM*KK; i += 256) ws_[i] = w[(size_t)be*NM*KK + i];
  __syncthreads();
  for (int idx = t; idx < KK*96; idx += 256){
    int k = idx % KK, d8 = idx / KK;     // lanes consecutive in k -> broadcast es reads
    int d0 = d8*8;
    float a[8] = {0,0,0,0,0,0,0,0};
    #pragma unroll
    for (int m=0;m<NM;m++){
      float wv = ws_[m*KK + k];
      #pragma unroll
      for (int j=0;j<8;j++) a[j] += wv*es[m*DD + d0 + j];
    }
    int row = be*KK + k;
    int mt = row >> 5, lr = row & 31, ds = d8 >> 1, qq = d8 & 1;
    short8 v;
    #pragma unroll
    for (int j=0;j<8;j++) v[j] = (short)f2bf(a[j]);
    *(short8*)(esf + ((((size_t)mt*48) + ds)*64 + lr + 32*qq)*8) = v;
  }
}

// ------------- K6: seqlin[b,l,c] = seq[b,l,:] . Wlin[:,c] -------------
__global__ void k_seqlin(const float* __restrict__ seq, const float* __restrict__ Wlin,
                         float* __restrict__ sl){
  int bl = blockIdx.x; int t = threadIdx.x;
  const float* row = seq + (size_t)bl*DD;
  float a[3] = {0.f,0.f,0.f};
  for (int dd=t; dd<DD; dd+=256){
    float v = row[dd];
    a[0] += v*Wlin[dd*3+0]; a[1] += v*Wlin[dd*3+1]; a[2] += v*Wlin[dd*3+2];
  }
  __shared__ float red[256];
  float res[3];
  for (int c=0;c<3;c++){
    red[t] = a[c]; __syncthreads();
    for (int off=128; off>0; off>>=1){ if (t<off) red[t]+=red[t+off]; __syncthreads(); }
    res[c] = red[0]; __syncthreads();
  }
  if (t==0){ sl[bl*3+0]=res[0]; sl[bl*3+1]=res[1]; sl[bl*3+2]=res[2]; }
}

// ------------- K5: fused ht einsum + row-normalize + x = htn@seqlin + blin -------------
__global__ void k_ht_x(const float* __restrict__ eas, const float* __restrict__ sl,
                       const float* __restrict__ blin, float* __restrict__ x){
  int idx = blockIdx.x;            // (b*NE+i)*NE + j
  int j = idx % NE; int i = (idx/NE)%NE; int b = idx/(NE*NE);
  int t = threadIdx.x;
  int w = t >> 6, lane = t & 63;
  const float* ai = eas + ((size_t)(b*NE+i))*HH*LL;
  const float* aj = eas + ((size_t)(b*NE+j))*HH*LL;
  float v[4];
  #pragma unroll
  for (int it=0; it<4; it++){
    int l = t + it*256;
    float acc=0.f;
    #pragma unroll
    for (int hh2=0; hh2<HH; hh2++) acc += ai[hh2*LL + l]*aj[hh2*LL + l];
    v[it] = acc * (1.f/HH);
  }
  __shared__ float wsum[4];
  __shared__ float xred[4][3];
  float s = v[0]+v[1]+v[2]+v[3];
  s += __shfl_xor(s, 1);  s += __shfl_xor(s, 2);  s += __shfl_xor(s, 4);
  s += __shfl_xor(s, 8);  s += __shfl_xor(s, 16); s += __shfl_xor(s, 32);
  if (lane == 0) wsum[w] = s;
  __syncthreads();
  float inv = 1.f/((wsum[0]+wsum[1]+wsum[2]+wsum[3]) + 1e-5f);
  float xa[3]={0.f,0.f,0.f};
  #pragma unroll
  for (int it=0; it<4; it++){
    int l = t + it*256;
    float wv = v[it]*inv;
    const float* s3 = sl + ((size_t)b*LL + l)*3;
    xa[0]+=wv*s3[0]; xa[1]+=wv*s3[1]; xa[2]+=wv*s3[2];
  }
  #pragma unroll
  for (int c=0;c<3;c++){
    float q = xa[c];
    q += __shfl_xor(q, 1);  q += __shfl_xor(q, 2);  q += __shfl_xor(q, 4);
    q += __shfl_xor(q, 8);  q += __shfl_xor(q, 16); q += __shfl_xor(q, 32);
    if (lane == 0) xred[w][c] = q;
  }
  __syncthreads();
  if (t < 3) x[(size_t)idx*3 + t] = xred[0][t]+xred[1][t]+xred[2][t]+xred[3][t] + blin[t];
}

// ------------- K8: 3x3x(3->256) conv + relu at gathered pairs -------------
__global__ void k_conv_pairs(const float* __restrict__ x, const int* __restrict__ pairs,
                             const float* __restrict__ Wseg, const float* __restrict__ bseg,
                             float* __restrict__ htss){
  int n = blockIdx.x; int t = threadIdx.x;   // t = f channel
  int b = n / PPAIR;
  int hi = pairs[n*2+0], ti = pairs[n*2+1];
  __shared__ float xs[27];
  if (t < 27){
    int di = t/9, dj = (t/3)%3, ci = t%3;
    int ii = hi + di - 1, jj = ti + dj - 1;
    float v = 0.f;
    if (ii>=0 && ii<NE && jj>=0 && jj<NE) v = x[(((size_t)b*NE+ii)*NE+jj)*3 + ci];
    xs[t] = v;
  }
  __syncthreads();
  float acc = bseg[t];
  #pragma unroll
  for (int tap=0; tap<27; tap++) acc += xs[tap]*Wseg[tap*FF + t];
  htss[(size_t)n*FF + t] = fmaxf(acc, 0.f);
}

// ------------- K9: pairh[n,:] = htss[n,:] @ W[768:1024,:] + bias -------------
__global__ void k_pair_proj(const float* __restrict__ htss, const float* __restrict__ Wb,
                            const float* __restrict__ bias, float* __restrict__ outp){
  int n = blockIdx.x; int t = threadIdx.x;
  __shared__ float hs_s[FF];
  hs_s[t] = htss[(size_t)n*FF + t];
  __syncthreads();
  float a0 = bias[t], a1 = bias[t+256], a2 = bias[t+512];
  for (int r=0;r<FF;r++){
    float hv = hs_s[r];
    const float* wr = Wb + (size_t)r*DD;
    a0 += hv*wr[t]; a1 += hv*wr[t+256]; a2 += hv*wr[t+512];
  }
  float* dst = outp + (size_t)n*DD;
  dst[t]=a0; dst[t+256]=a1; dst[t+512]=a2;
}

// ------- K-shuffle: fp32 [768(k)][768(n)] -> bf16 B-frag order -------
// dst[ds(48)][nt(24)][lane(64)][j(8)]: lane = (n&31)+32*((k>>3)&1), j=k&7
__global__ void k_wshuffle(const float* __restrict__ src, unsigned short* __restrict__ dst){
  int bi = blockIdx.x;
  int mat = bi / 144; int r = bi % 144;
  int ds = r / 3, ntg = r % 3;
  int t = threadIdx.x;
  size_t mo = (size_t)mat*589824;
  __shared__ float ls[16][260];
  #pragma unroll
  for (int i=0;i<16;i++)
    ls[i][t] = src[mo + ((size_t)(ds*16+i))*768 + ntg*256 + t];
  __syncthreads();
  #pragma unroll
  for (int it=0; it<2; it++){
    int idx = it*256 + t;           // 0..511
    int pt_l = idx >> 6, lane = idx & 63;
    int nl = pt_l*32 + (lane & 31);
    int qq = lane >> 5;
    short8 v;
    #pragma unroll
    for (int j=0;j<8;j++) v[j] = (short)f2bf(ls[qq*8 + j][nl]);
    *(short8*)(dst + mo + (((size_t)ds*24 + ntg*8 + pt_l)*64 + lane)*8) = v;
  }
}

// ------------- K10: C_bf16[M,768] = A_frag @ B_frag (32x32x16 MFMA, LDS-free) -------------
__global__ __launch_bounds__(256) void k_gemm_frag(const unsigned short* __restrict__ Af,
    const unsigned short* __restrict__ Bf, unsigned short* __restrict__ C){
  int mt = blockIdx.x / 6, ntg = blockIdx.x % 6;
  int t = threadIdx.x; int w = t >> 6; int lane = t & 63;
  int nt = ntg*4 + w;
  float16 acc = (float16)(0.0f);
  const unsigned short* ap = Af + (((size_t)mt*48)*64 + lane)*8;
  const unsigned short* bp = Bf + (((size_t)nt)*64 + lane)*8;
  #pragma unroll 4
  for (int ds=0; ds<48; ds++){
    short8 a = *(const short8*)(ap + (size_t)ds*512);
    short8 b = *(const short8*)(bp + (size_t)ds*24*512);
    acc = __builtin_amdgcn_mfma_f32_32x32x16_bf16(a, b, acc, 0, 0, 0);
  }
  int col = nt*32 + (lane & 31);
  int aq = lane >> 5;
  #pragma unroll
  for (int rI=0;rI<16;rI++){
    int row = mt*32 + (rI&3) + 8*(rI>>2) + 4*aq;
    C[(size_t)row*768 + col] = f2bf(acc[rI]);
  }
}

// ------------- K11a: hsF[nt,k,ds,lane,8] = tanh(Ehb[ent(n),k,d] + ph[n,d]) as A-frag bf16 -------------
// grid: NT32 * KK blocks, 256 thr. lane = (row&31) + 32*((d>>3)&1), j = d&7, ds = d>>4
__global__ void k_hsts(const unsigned short* __restrict__ Ehb, const float* __restrict__ ph,
                       const int* __restrict__ pairs, unsigned short* __restrict__ hsF){
  int bi = blockIdx.x; int nt = bi / KK; int k = bi - nt*KK;
  int t = threadIdx.x;
  __shared__ int ehB[32];
  if (t < 32){
    int n = nt*32 + t; int b = n >> 7;
    ehB[t] = ((b*NE + pairs[n*2+0])*KK + k)*DD;
  }
  __syncthreads();
  unsigned short* dst = hsF + (((size_t)nt*KK + k)*48)*512;
  #pragma unroll 2
  for (int c=0; c<12; c++){
    int L = c*256 + t;
    int ds = L >> 6, lane = L & 63;
    int r = lane & 31, q = lane >> 5;
    int n = nt*32 + r;
    int d0 = ds*16 + q*8;
    short8 ev = *(const short8*)(Ehb + ehB[r] + d0);
    float4 p0 = *(const float4*)(ph + (size_t)n*DD + d0);
    float4 p1 = *(const float4*)(ph + (size_t)n*DD + d0 + 4);
    float pf[8] = {p0.x,p0.y,p0.z,p0.w,p1.x,p1.y,p1.z,p1.w};
    short8 v;
    #pragma unroll
    for (int j=0;j<8;j++) v[j] = (short)f2bf(fast_tanh(bf2f((unsigned short)ev[j]) + pf[j]));
    *(short8*)(dst + (size_t)ds*512 + lane*8) = v;
  }
}

// ------------- K11b: out[n,k] = bias[k] (atomic accumulation target) -------------
__global__ void k_outinit(const float* __restrict__ bias, float* __restrict__ out){
  int i = blockIdx.x*256 + threadIdx.x;
  if (i < NPAIR*KK) out[i] = bias[i % KK];
}

// ------------- K11c: bilinear GEMM, p-split + atomicAdd partials -------------
// 512 thr = 8 waves: wr=w>>1 (4 row-tiles of 32 -> 128 rows/block), wc=w&1 (p parity).
// p-range: 6 tiles per ps; wave's tiles = ps*6 + wc + {0,2,4} -> 3 accs (48 AGPR).
// XCD-aligned: blockIdx&7 == k%8 so all 16 blocks sharing BF[k] share one L2.
__global__ __launch_bounds__(512,4) void k_bil_gemm(
    const unsigned short* __restrict__ hsF, const unsigned short* __restrict__ Etb,
    const float* __restrict__ pt_, const unsigned short* __restrict__ Bfrag,
    const int* __restrict__ pairs, float* __restrict__ out){
  int xcd = blockIdx.x & 7; int g = blockIdx.x >> 3;
  int ps = g & 3; int nt = (g >> 2) & 3; int kgrp = g >> 4;
  int k = kgrp*8 + xcd;
  if (k >= KK) return;
  int n0 = nt*128;
  int t = threadIdx.x; int w = t >> 6; int lane = t & 63;
  int wr = w >> 1, wc = w & 1;
  __shared__ int etB[128];
  __shared__ float redbuf[4][2][32];
  if (t < 128){
    int n = n0 + t; int b = n >> 7;
    etB[t] = ((b*NE + pairs[n*2+1])*KK + k)*DD;
  }
  __syncthreads();
  int aq = lane >> 5;
  int mt = nt*4 + wr;
  const unsigned short* ap = hsF + (((size_t)mt*KK + k)*48)*512 + lane*8;
  const unsigned short* bb = Bfrag + (size_t)k*589824 + (size_t)lane*8;
  int pb0 = ps*6 + wc;                 // tiles pb0, pb0+2, pb0+4
  float16 acc0 = (float16)(0.f), acc1 = (float16)(0.f), acc2 = (float16)(0.f);
  #pragma unroll 4
  for (int ds=0; ds<48; ds++){
    short8 a = *(const short8*)(ap + (size_t)ds*512);
    const unsigned short* bds = bb + (size_t)ds*24*512;
    short8 b0 = *(const short8*)(bds + (size_t)(pb0+0)*512);
    short8 b1 = *(const short8*)(bds + (size_t)(pb0+2)*512);
    short8 b2 = *(const short8*)(bds + (size_t)(pb0+4)*512);
    acc0 = __builtin_amdgcn_mfma_f32_32x32x16_bf16(a, b0, acc0, 0, 0, 0);
    acc1 = __builtin_amdgcn_mfma_f32_32x32x16_bf16(a, b1, acc1, 0, 0, 0);
    acc2 = __builtin_amdgcn_mfma_f32_32x32x16_bf16(a, b2, acc2, 0, 0, 0);
  }
  // epilogue: s = sum over this wave's 3 p-tiles of U[row,p]*tanh(Et+pt)[row,p]
  #pragma unroll
  for (int rI=0; rI<16; rI++){
    int row = (rI&3) + 8*(rI>>2) + 4*aq;   // 0..31 within wave's row-tile
    int nloc = wr*32 + row;
    int eb = etB[nloc];
    const float* ptp = pt_ + (size_t)(n0 + nloc)*DD;
    int colb = lane & 31;
    int c0 = (pb0+0)*32 + colb, c1 = (pb0+2)*32 + colb, c2 = (pb0+4)*32 + colb;
    float s = acc0[rI]*fast_tanh(bf2f(Etb[eb + c0]) + ptp[c0])
            + acc1[rI]*fast_tanh(bf2f(Etb[eb + c1]) + ptp[c1])
            + acc2[rI]*fast_tanh(bf2f(Etb[eb + c2]) + ptp[c2]);
    s += __shfl_xor(s, 1);  s += __shfl_xor(s, 2);
    s += __shfl_xor(s, 4);  s += __shfl_xor(s, 8);
    s += __shfl_xor(s, 16);
    if ((lane & 31) == 0) redbuf[wr][wc][row] = s;
  }
  __syncthreads();
  if (t < 128){
    atomicAdd(&out[(size_t)(n0 + t)*KK + k],
              redbuf[t>>5][0][t&31] + redbuf[t>>5][1][t&31]);
  }
}

extern "C" void kernel_launch(void* const* d_in, const int* in_sizes, int n_in,
                              void* d_out, int out_size, void* d_ws, size_t ws_size,
                              hipStream_t stream){
  const float* seq      = (const float*)d_in[0];
  const float* att      = (const float*)d_in[1];
  const float* mask     = (const float*)d_in[2];
  const int*   mpos     = (const int*)d_in[3];
  const int*   pairs    = (const int*)d_in[4];
  const float* Wattn    = (const float*)d_in[5];
  const float* battn    = (const float*)d_in[6];
  const float* attn_net = (const float*)d_in[7];
  const float* Wlin     = (const float*)d_in[8];
  const float* blin     = (const float*)d_in[9];
  const float* Wseg     = (const float*)d_in[10];
  const float* bseg     = (const float*)d_in[11];
  const float* Whead    = (const float*)d_in[12];
  const float* bhead    = (const float*)d_in[13];
  const float* Wtail    = (const float*)d_in[14];
  const float* btail    = (const float*)d_in[15];
  const float* bil      = (const float*)d_in[16];
  const float* bilb     = (const float*)d_in[17];
  float* out = (float*)d_out;

  char* ws = (char*)d_ws;
  size_t off = 0;
  auto allocB = [&](size_t nbytes)->char*{
    char* p = ws + off;
    off += (nbytes + 255) & ~(size_t)255;
    return p;
  };
  // ---- persistent (live across the bilinear path) ----
  unsigned short* BF     = (unsigned short*)allocB((size_t)KK*589824*2);    // 114.4 MB
  unsigned short* Ehb    = (unsigned short*)allocB((size_t)MT*32*768*2);    // 25 MB
  unsigned short* Etb    = (unsigned short*)allocB((size_t)MT*32*768*2);    // 25 MB
  unsigned short* WheadF = (unsigned short*)allocB((size_t)589824*2);
  unsigned short* WtailF = (unsigned short*)allocB((size_t)589824*2);
  float* phb  = (float*)allocB((size_t)NPAIR*DD*4);
  float* ptb  = (float*)allocB((size_t)NPAIR*DD*4);
  // ---- union region: {emb,tbuf,wsm,eas,sl,xb,htss,esf} all dead before k_hsts writes hsF ----
  size_t hsF_bytes = (size_t)NT32*KK*48*512*2;                              // 76.3 MB
  char* uni = allocB(hsF_bytes);
  size_t uoff = 0;
  auto ualloc = [&](size_t nbytes)->char*{
    char* p = uni + uoff;
    uoff += (nbytes + 255) & ~(size_t)255;
    return p;
  };
  float* emb  = (float*)ualloc((size_t)BS*NE*NM*DD*4);
  float* tbuf = (float*)ualloc((size_t)BS*NE*NM*RR*4);
  float* wsm  = (float*)ualloc((size_t)BS*NE*NM*KK*4);
  float* eas  = (float*)ualloc((size_t)BS*NE*HH*LL*4);
  float* sl   = (float*)ualloc((size_t)BS*LL*3*4);
  float* xb   = (float*)ualloc((size_t)BS*NE*NE*3*4);
  float* htss = (float*)ualloc((size_t)NPAIR*FF*4);
  unsigned short* esf = (unsigned short*)ualloc((size_t)MT*48*64*8*2);      // 25 MB
  unsigned short* hsF = (unsigned short*)uni;                               // aliases scratch

  k_outinit<<<(NPAIR*KK+255)/256, 256, 0, stream>>>(bilb, out);
  k_emb<<<BS*NE*NM, 256, 0, stream>>>(seq, mpos, mask, emb);
  k_score1<<<BS*NE*NM, 256, 0, stream>>>(emb, Wattn, battn, tbuf);
  k_scores<<<BS*NE, 128, 0, stream>>>(tbuf, attn_net, mask, wsm);
  k_entity_as<<<BS*NE*HH, 256, 0, stream>>>(att, mpos, mask, eas);
  k_entity_es<<<BS*NE, 256, 0, stream>>>(emb, wsm, esf);
  k_seqlin<<<BS*LL, 256, 0, stream>>>(seq, Wlin, sl);
  k_ht_x<<<BS*NE*NE, 256, 0, stream>>>(eas, sl, blin, xb);
  k_conv_pairs<<<NPAIR, 256, 0, stream>>>(xb, pairs, Wseg, bseg, htss);
  k_pair_proj<<<NPAIR, 256, 0, stream>>>(htss, Whead + 768*768, bhead, phb);
  k_pair_proj<<<NPAIR, 256, 0, stream>>>(htss, Wtail + 768*768, btail, ptb);
  k_wshuffle<<<144, 256, 0, stream>>>(Whead, WheadF);
  k_wshuffle<<<144, 256, 0, stream>>>(Wtail, WtailF);
  k_wshuffle<<<KK*144, 256, 0, stream>>>(bil, BF);
  k_gemm_frag<<<MT*6, 256, 0, stream>>>(esf, WheadF, Ehb);
  k_gemm_frag<<<MT*6, 256, 0, stream>>>(esf, WtailF, Etb);
  k_hsts<<<NT32*KK, 256, 0, stream>>>(Ehb, phb, pairs, hsF);   // esf dead; hsF overwrites union
  k_bil_gemm<<<GRID_BG, 512, 0, stream>>>(hsF, Etb, ptb, BF, pairs, out);
}

// Round 3
// 892.937 us; speedup vs baseline: 1.3926x; 1.0869x over previous
//
#include <hip/hip_runtime.h>
#include <hip/hip_bf16.h>

#define BS 4
#define LL 1024
#define DD 768
#define HH 12
#define NE 42
#define NM 8
#define KK 97
#define PPAIR 128
#define FF 256
#define RR 256
#define NPAIR (BS*PPAIR)     // 512
#define MROWS (BS*NE*KK)     // 16296
#define MT 510               // ceil(16296/32)
#define NT32 16              // 512 pair-rows / 32
#define GRID_BG (8*13*16)    // xcd(8) x kgrp(13) x nt128(4) x ps(4) = 1664

typedef __attribute__((ext_vector_type(8))) short short8;
typedef __attribute__((ext_vector_type(16))) float float16;

__device__ __forceinline__ float fast_tanh(float x){
  x = fminf(fmaxf(x, -15.f), 15.f);
  float e = __expf(2.f*x);
  return 1.f - 2.f/(e + 1.f);
}
__device__ __forceinline__ unsigned short f2bf(float f){
  unsigned int u = __float_as_uint(f);
  unsigned int r = (u + 0x7FFF + ((u>>16)&1)) >> 16;
  return (unsigned short)r;
}
__device__ __forceinline__ float bf2f(unsigned short u){
  return __uint_as_float(((unsigned int)u)<<16);
}
// async global->LDS, 16B per lane; lds base must be wave-uniform
__device__ __forceinline__ void stage16(const void* g, void* l){
  __builtin_amdgcn_global_load_lds(
      (const __attribute__((address_space(1))) void*)g,
      (__attribute__((address_space(3))) void*)l, 16, 0, 0);
}

// ---------------- K1: emb[b,e,m,:] = seq[b,pos,:] * mask ----------------
__global__ void k_emb(const float* __restrict__ seq, const int* __restrict__ mpos,
                      const float* __restrict__ mask, float* __restrict__ emb){
  int idx = blockIdx.x;            // (b*NE+e)*NM+m
  int t = threadIdx.x;
  int b = idx / (NE*NM);
  float mk = mask[idx];
  int pos = mpos[idx] + 1;
  pos = min(max(pos, 0), LL-1);
  const float* src = seq + ((size_t)b*LL + pos)*DD;
  float* dst = emb + (size_t)idx*DD;
  for (int dd = t; dd < DD; dd += 256) dst[dd] = mk * src[dd];
}

// ------------- K2: entity_as[b,e,h,l] = sum_m mask*att[b,h,pos,l]/cnt -------------
__global__ void k_entity_as(const float* __restrict__ att, const int* __restrict__ mpos,
                            const float* __restrict__ mask, float* __restrict__ eas){
  int idx = blockIdx.x;            // (b*NE+e)*HH + hh
  int hh = idx % HH; int be = idx / HH;
  int b = be / NE;
  int t = threadIdx.x;
  float cnt = 0.f;
  for (int m=0;m<NM;m++) cnt += mask[be*NM+m];
  float inv = 1.f / fmaxf(cnt, 1.f);
  float acc[4] = {0.f,0.f,0.f,0.f};
  for (int m=0;m<NM;m++){
    float mk = mask[be*NM+m];
    if (mk != 0.f){
      int pos = min(max(mpos[be*NM+m]+1,0), LL-1);
      const float* row = att + (((size_t)b*HH + hh)*LL + pos)*LL;
      acc[0] += mk*row[t]; acc[1] += mk*row[t+256];
      acc[2] += mk*row[t+512]; acc[3] += mk*row[t+768];
    }
  }
  float* dst = eas + (size_t)idx*LL;
  dst[t]=acc[0]*inv; dst[t+256]=acc[1]*inv; dst[t+512]=acc[2]*inv; dst[t+768]=acc[3]*inv;
}

// ------------- K3a: tbuf[b,e,m,r] = tanh(emb . Wattn[:,r] + battn[r]) -------------
__global__ void k_score1(const float* __restrict__ emb, const float* __restrict__ Wattn,
                         const float* __restrict__ battn, float* __restrict__ tbuf){
  int idx = blockIdx.x; int t = threadIdx.x;  // 256 threads, r = t
  __shared__ float es[DD];
  es[t]       = emb[(size_t)idx*DD + t];
  es[t+256]   = emb[(size_t)idx*DD + t + 256];
  es[t+512]   = emb[(size_t)idx*DD + t + 512];
  __syncthreads();
  float acc = battn[t];
  for (int dd=0; dd<DD; dd++) acc += es[dd]*Wattn[dd*RR + t];
  tbuf[(size_t)idx*RR + t] = fast_tanh(acc);
}

// ------------- K3b: scores + masked softmax over mentions -> w[b,e,m,k] -------------
__global__ void k_scores(const float* __restrict__ tbuf, const float* __restrict__ an,
                         const float* __restrict__ mask, float* __restrict__ w){
  int be = blockIdx.x; int t = threadIdx.x;   // 128 threads
  __shared__ float ts_[NM*RR];                // 8 KB
  __shared__ float an_s[64*98];               // 25 KB chunk of attn_net^T
  for (int i=t; i<NM*RR; i+=128) ts_[i] = tbuf[(size_t)be*NM*RR + i];
  float acc[NM];
  #pragma unroll
  for (int m=0;m<NM;m++) acc[m] = 0.f;
  for (int rc=0; rc<RR; rc+=64){
    __syncthreads();
    for (int i=t; i<KK*64; i+=128){
      int kq = i >> 6, r = i & 63;
      an_s[r*98 + kq] = an[kq*RR + rc + r];
    }
    __syncthreads();
    if (t < KK){
      for (int m=0;m<NM;m++){
        float a = 0.f;
        for (int r=0;r<64;r++) a += ts_[m*RR + rc + r]*an_s[r*98 + t];
        acc[m] += a;
      }
    }
  }
  if (t < KK){
    float s[NM];
    #pragma unroll
    for (int m=0;m<NM;m++){
      float mk = mask[be*NM+m];
      s[m] = acc[m] + (1.f - mk)*(-1e6f);
    }
    float mx = s[0];
    #pragma unroll
    for (int m=1;m<NM;m++) mx = fmaxf(mx, s[m]);
    float sum = 0.f; float e[NM];
    #pragma unroll
    for (int m=0;m<NM;m++){ e[m] = __expf(s[m]-mx); sum += e[m]; }
    float invs = 1.f/sum;
    #pragma unroll
    for (int m=0;m<NM;m++) w[((size_t)be*NM+m)*KK + t] = e[m]*invs;
  }
}

// ------- K4: entity_es -> bf16 in A-fragment order for 32x32x16 MFMA -------
// es_frag[mt][ds][lane][8]: lane = (row&31) + 32*((d>>3)&1), j = d&7, ds = d>>4
__global__ void k_entity_es(const float* __restrict__ emb, const float* __restrict__ w,
                            unsigned short* __restrict__ esf){
  int be = blockIdx.x; int t = threadIdx.x;
  __shared__ float es[NM*DD];    // 24 KB
  __shared__ float ws_[NM*KK];
  for (int i = t; i < NM*DD; i += 256) es[i] = emb[(size_t)be*NM*DD + i];
  for (int i = t; i < NM*KK; i += 256) ws_[i] = w[(size_t)be*NM*KK + i];
  __syncthreads();
  for (int idx = t; idx < KK*96; idx += 256){
    int k = idx % KK, d8 = idx / KK;     // lanes consecutive in k -> broadcast es reads
    int d0 = d8*8;
    float a[8] = {0,0,0,0,0,0,0,0};
    #pragma unroll
    for (int m=0;m<NM;m++){
      float wv = ws_[m*KK + k];
      #pragma unroll
      for (int j=0;j<8;j++) a[j] += wv*es[m*DD + d0 + j];
    }
    int row = be*KK + k;
    int mt = row >> 5, lr = row & 31, ds = d8 >> 1, qq = d8 & 1;
    short8 v;
    #pragma unroll
    for (int j=0;j<8;j++) v[j] = (short)f2bf(a[j]);
    *(short8*)(esf + ((((size_t)mt*48) + ds)*64 + lr + 32*qq)*8) = v;
  }
}

// ------------- K6: seqlin[b,l,c] = seq[b,l,:] . Wlin[:,c] -------------
__global__ void k_seqlin(const float* __restrict__ seq, const float* __restrict__ Wlin,
                         float* __restrict__ sl){
  int bl = blockIdx.x; int t = threadIdx.x;
  const float* row = seq + (size_t)bl*DD;
  float a[3] = {0.f,0.f,0.f};
  for (int dd=t; dd<DD; dd+=256){
    float v = row[dd];
    a[0] += v*Wlin[dd*3+0]; a[1] += v*Wlin[dd*3+1]; a[2] += v*Wlin[dd*3+2];
  }
  __shared__ float red[256];
  float res[3];
  for (int c=0;c<3;c++){
    red[t] = a[c]; __syncthreads();
    for (int off=128; off>0; off>>=1){ if (t<off) red[t]+=red[t+off]; __syncthreads(); }
    res[c] = red[0]; __syncthreads();
  }
  if (t==0){ sl[bl*3+0]=res[0]; sl[bl*3+1]=res[1]; sl[bl*3+2]=res[2]; }
}

// ------------- K5: fused ht einsum + row-normalize + x = htn@seqlin + blin -------------
__global__ void k_ht_x(const float* __restrict__ eas, const float* __restrict__ sl,
                       const float* __restrict__ blin, float* __restrict__ x){
  int idx = blockIdx.x;            // (b*NE+i)*NE + j
  int j = idx % NE; int i = (idx/NE)%NE; int b = idx/(NE*NE);
  int t = threadIdx.x;
  int w = t >> 6, lane = t & 63;
  const float* ai = eas + ((size_t)(b*NE+i))*HH*LL;
  const float* aj = eas + ((size_t)(b*NE+j))*HH*LL;
  float v[4];
  #pragma unroll
  for (int it=0; it<4; it++){
    int l = t + it*256;
    float acc=0.f;
    #pragma unroll
    for (int hh2=0; hh2<HH; hh2++) acc += ai[hh2*LL + l]*aj[hh2*LL + l];
    v[it] = acc * (1.f/HH);
  }
  __shared__ float wsum[4];
  __shared__ float xred[4][3];
  float s = v[0]+v[1]+v[2]+v[3];
  s += __shfl_xor(s, 1);  s += __shfl_xor(s, 2);  s += __shfl_xor(s, 4);
  s += __shfl_xor(s, 8);  s += __shfl_xor(s, 16); s += __shfl_xor(s, 32);
  if (lane == 0) wsum[w] = s;
  __syncthreads();
  float inv = 1.f/((wsum[0]+wsum[1]+wsum[2]+wsum[3]) + 1e-5f);
  float xa[3]={0.f,0.f,0.f};
  #pragma unroll
  for (int it=0; it<4; it++){
    int l = t + it*256;
    float wv = v[it]*inv;
    const float* s3 = sl + ((size_t)b*LL + l)*3;
    xa[0]+=wv*s3[0]; xa[1]+=wv*s3[1]; xa[2]+=wv*s3[2];
  }
  #pragma unroll
  for (int c=0;c<3;c++){
    float q = xa[c];
    q += __shfl_xor(q, 1);  q += __shfl_xor(q, 2);  q += __shfl_xor(q, 4);
    q += __shfl_xor(q, 8);  q += __shfl_xor(q, 16); q += __shfl_xor(q, 32);
    if (lane == 0) xred[w][c] = q;
  }
  __syncthreads();
  if (t < 3) x[(size_t)idx*3 + t] = xred[0][t]+xred[1][t]+xred[2][t]+xred[3][t] + blin[t];
}

// ------------- K8: 3x3x(3->256) conv + relu at gathered pairs -------------
__global__ void k_conv_pairs(const float* __restrict__ x, const int* __restrict__ pairs,
                             const float* __restrict__ Wseg, const float* __restrict__ bseg,
                             float* __restrict__ htss){
  int n = blockIdx.x; int t = threadIdx.x;   // t = f channel
  int b = n / PPAIR;
  int hi = pairs[n*2+0], ti = pairs[n*2+1];
  __shared__ float xs[27];
  if (t < 27){
    int di = t/9, dj = (t/3)%3, ci = t%3;
    int ii = hi + di - 1, jj = ti + dj - 1;
    float v = 0.f;
    if (ii>=0 && ii<NE && jj>=0 && jj<NE) v = x[(((size_t)b*NE+ii)*NE+jj)*3 + ci];
    xs[t] = v;
  }
  __syncthreads();
  float acc = bseg[t];
  #pragma unroll
  for (int tap=0; tap<27; tap++) acc += xs[tap]*Wseg[tap*FF + t];
  htss[(size_t)n*FF + t] = fmaxf(acc, 0.f);
}

// ------------- K9: pairh[n,:] = htss[n,:] @ W[768:1024,:] + bias -------------
__global__ void k_pair_proj(const float* __restrict__ htss, const float* __restrict__ Wb,
                            const float* __restrict__ bias, float* __restrict__ outp){
  int n = blockIdx.x; int t = threadIdx.x;
  __shared__ float hs_s[FF];
  hs_s[t] = htss[(size_t)n*FF + t];
  __syncthreads();
  float a0 = bias[t], a1 = bias[t+256], a2 = bias[t+512];
  for (int r=0;r<FF;r++){
    float hv = hs_s[r];
    const float* wr = Wb + (size_t)r*DD;
    a0 += hv*wr[t]; a1 += hv*wr[t+256]; a2 += hv*wr[t+512];
  }
  float* dst = outp + (size_t)n*DD;
  dst[t]=a0; dst[t+256]=a1; dst[t+512]=a2;
}

// ------- K-shuffle: fp32 [768(k)][768(n)] -> bf16 B-frag order -------
// dst[ds(48)][nt(24)][lane(64)][j(8)]: lane = (n&31)+32*((k>>3)&1), j=k&7
__global__ void k_wshuffle(const float* __restrict__ src, unsigned short* __restrict__ dst){
  int bi = blockIdx.x;
  int mat = bi / 144; int r = bi % 144;
  int ds = r / 3, ntg = r % 3;
  int t = threadIdx.x;
  size_t mo = (size_t)mat*589824;
  __shared__ float ls[16][260];
  #pragma unroll
  for (int i=0;i<16;i++)
    ls[i][t] = src[mo + ((size_t)(ds*16+i))*768 + ntg*256 + t];
  __syncthreads();
  #pragma unroll
  for (int it=0; it<2; it++){
    int idx = it*256 + t;           // 0..511
    int pt_l = idx >> 6, lane = idx & 63;
    int nl = pt_l*32 + (lane & 31);
    int qq = lane >> 5;
    short8 v;
    #pragma unroll
    for (int j=0;j<8;j++) v[j] = (short)f2bf(ls[qq*8 + j][nl]);
    *(short8*)(dst + mo + (((size_t)ds*24 + ntg*8 + pt_l)*64 + lane)*8) = v;
  }
}

// ------------- K10: both C_bf16[M,768] = A_frag @ {Bh,Bt} (shared A stream) -------------
__global__ __launch_bounds__(256) void k_gemm_frag2(const unsigned short* __restrict__ Af,
    const unsigned short* __restrict__ Bh, const unsigned short* __restrict__ Bt,
    unsigned short* __restrict__ Ch, unsigned short* __restrict__ Ct){
  int mt = blockIdx.x / 6, ntg = blockIdx.x % 6;
  int t = threadIdx.x; int w = t >> 6; int lane = t & 63;
  int nt = ntg*4 + w;
  float16 acch = (float16)(0.0f), acct = (float16)(0.0f);
  const unsigned short* ap = Af + (((size_t)mt*48)*64 + lane)*8;
  const unsigned short* bph = Bh + (((size_t)nt)*64 + lane)*8;
  const unsigned short* bpt = Bt + (((size_t)nt)*64 + lane)*8;
  #pragma unroll 4
  for (int ds=0; ds<48; ds++){
    short8 a  = *(const short8*)(ap + (size_t)ds*512);
    short8 bh = *(const short8*)(bph + (size_t)ds*24*512);
    short8 bt = *(const short8*)(bpt + (size_t)ds*24*512);
    acch = __builtin_amdgcn_mfma_f32_32x32x16_bf16(a, bh, acch, 0, 0, 0);
    acct = __builtin_amdgcn_mfma_f32_32x32x16_bf16(a, bt, acct, 0, 0, 0);
  }
  int col = nt*32 + (lane & 31);
  int aq = lane >> 5;
  #pragma unroll
  for (int rI=0;rI<16;rI++){
    int row = mt*32 + (rI&3) + 8*(rI>>2) + 4*aq;
    Ch[(size_t)row*768 + col] = f2bf(acch[rI]);
    Ct[(size_t)row*768 + col] = f2bf(acct[rI]);
  }
}

// ------------- K11a: hsF[nt,k,ds,lane,8] = tanh(Ehb[ent(n),k,d] + ph[n,d]) as A-frag bf16 -------------
__global__ void k_hsts(const unsigned short* __restrict__ Ehb, const float* __restrict__ ph,
                       const int* __restrict__ pairs, unsigned short* __restrict__ hsF){
  int bi = blockIdx.x; int nt = bi / KK; int k = bi - nt*KK;
  int t = threadIdx.x;
  __shared__ int ehB[32];
  if (t < 32){
    int n = nt*32 + t; int b = n >> 7;
    ehB[t] = ((b*NE + pairs[n*2+0])*KK + k)*DD;
  }
  __syncthreads();
  unsigned short* dst = hsF + (((size_t)nt*KK + k)*48)*512;
  #pragma unroll 2
  for (int c=0; c<12; c++){
    int L = c*256 + t;
    int ds = L >> 6, lane = L & 63;
    int r = lane & 31, q = lane >> 5;
    int n = nt*32 + r;
    int d0 = ds*16 + q*8;
    short8 ev = *(const short8*)(Ehb + ehB[r] + d0);
    float4 p0 = *(const float4*)(ph + (size_t)n*DD + d0);
    float4 p1 = *(const float4*)(ph + (size_t)n*DD + d0 + 4);
    float pf[8] = {p0.x,p0.y,p0.z,p0.w,p1.x,p1.y,p1.z,p1.w};
    short8 v;
    #pragma unroll
    for (int j=0;j<8;j++) v[j] = (short)f2bf(fast_tanh(bf2f((unsigned short)ev[j]) + pf[j]));
    *(short8*)(dst + (size_t)ds*512 + lane*8) = v;
  }
}

// ------------- K11b: out[n,k] = bias[k] (atomic accumulation target) -------------
__global__ void k_outinit(const float* __restrict__ bias, float* __restrict__ out){
  int i = blockIdx.x*256 + threadIdx.x;
  if (i < NPAIR*KK) out[i] = bias[i % KK];
}

// ------------- K11c: bilinear GEMM, LDS-staged (2-phase, counted vmcnt) -------------
// 512 thr = 8 waves: wr=w>>1 (4 row-tiles -> 128 rows), wc=w&1 (p parity).
// Per ds-step: 10x 1KB chunks staged via global_load_lds (4 A tiles + 6 B tiles),
// double-buffered; all waves consume via ds_read_b128. vmcnt never drained to 0
// in the main loop (T3/T4). XCD-aligned: blockIdx&7 == k%8 -> BF[k] L2-resident.
__global__ __launch_bounds__(512,4) void k_bil_gemm(
    const unsigned short* __restrict__ hsF, const unsigned short* __restrict__ Etb,
    const float* __restrict__ pt_, const unsigned short* __restrict__ Bfrag,
    const int* __restrict__ pairs, float* __restrict__ out){
  int xcd = blockIdx.x & 7; int g = blockIdx.x >> 3;
  int ps = g & 3; int nt = (g >> 2) & 3; int kgrp = g >> 4;
  int k = kgrp*8 + xcd;
  if (k >= KK) return;
  int n0 = nt*128;
  int t = threadIdx.x; int w = t >> 6; int lane = t & 63;
  int wr = w >> 1, wc = w & 1;
  __shared__ int etB[128];
  __shared__ unsigned short aS[2][4][512];   // 8 KB
  __shared__ unsigned short bS[2][6][512];   // 12 KB
  __shared__ float redbuf[4][2][32];
  if (t < 128){
    int n = n0 + t; int b = n >> 7;
    etB[t] = ((b*NE + pairs[n*2+1])*KK + k)*DD;
  }
  __syncthreads();
  int aq = lane >> 5;
  // per-wave stage chunk bases (global side, +lane*16B); lds dest is wave-uniform
  const unsigned short* gp0;
  unsigned short* lp0s[2];
  const unsigned short* gp1 = nullptr;
  unsigned short* lp1s[2] = {nullptr, nullptr};
  size_t gstep0, gstep1 = 0;
  if (w < 4){           // A chunk mt = nt*4 + w
    gp0 = hsF + (((size_t)(nt*4 + w)*KK + k)*48)*512 + lane*8;
    gstep0 = 512;
    lp0s[0] = &aS[0][w][0]; lp0s[1] = &aS[1][w][0];
  } else {              // B chunk j = w-4
    gp0 = Bfrag + ((size_t)k*1152 + (size_t)(ps*6 + (w-4)))*512 + lane*8;
    gstep0 = 24*512;
    lp0s[0] = &bS[0][w-4][0]; lp0s[1] = &bS[1][w-4][0];
  }
  int nch = 1;
  if (w < 2){           // second chunk: B j = 4+w
    gp1 = Bfrag + ((size_t)k*1152 + (size_t)(ps*6 + 4 + w))*512 + lane*8;
    gstep1 = 24*512;
    lp1s[0] = &bS[0][4+w][0]; lp1s[1] = &bS[1][4+w][0];
    nch = 2;
  }
  float16 acc0 = (float16)(0.f), acc1 = (float16)(0.f), acc2 = (float16)(0.f);
  // prologue: stage ds=0 into buf0
  stage16(gp0, lp0s[0]);
  if (nch == 2) stage16(gp1, lp1s[0]);
  for (int ds=0; ds<48; ds++){
    int buf = ds & 1;
    if (ds < 47){
      stage16(gp0 + (size_t)(ds+1)*gstep0, lp0s[buf^1]);
      if (nch == 2) stage16(gp1 + (size_t)(ds+1)*gstep1, lp1s[buf^1]);
      if (nch == 2) asm volatile("s_waitcnt vmcnt(2)" ::: "memory");
      else          asm volatile("s_waitcnt vmcnt(1)" ::: "memory");
    } else {
      asm volatile("s_waitcnt vmcnt(0)" ::: "memory");
    }
    asm volatile("s_barrier" ::: "memory");
    short8 a  = *(const short8*)&aS[buf][wr][lane*8];
    short8 b0 = *(const short8*)&bS[buf][wc  ][lane*8];
    short8 b1 = *(const short8*)&bS[buf][wc+2][lane*8];
    short8 b2 = *(const short8*)&bS[buf][wc+4][lane*8];
    acc0 = __builtin_amdgcn_mfma_f32_32x32x16_bf16(a, b0, acc0, 0, 0, 0);
    acc1 = __builtin_amdgcn_mfma_f32_32x32x16_bf16(a, b1, acc1, 0, 0, 0);
    acc2 = __builtin_amdgcn_mfma_f32_32x32x16_bf16(a, b2, acc2, 0, 0, 0);
    asm volatile("s_barrier" ::: "memory");
  }
  int pb0 = ps*6 + wc;                 // tiles pb0, pb0+2, pb0+4
  // epilogue: s = sum over this wave's 3 p-tiles of U[row,p]*tanh(Et+pt)[row,p]
  #pragma unroll
  for (int rI=0; rI<16; rI++){
    int row = (rI&3) + 8*(rI>>2) + 4*aq;   // 0..31 within wave's row-tile
    int nloc = wr*32 + row;
    int eb = etB[nloc];
    const float* ptp = pt_ + (size_t)(n0 + nloc)*DD;
    int colb = lane & 31;
    int c0 = (pb0+0)*32 + colb, c1 = (pb0+2)*32 + colb, c2 = (pb0+4)*32 + colb;
    float s = acc0[rI]*fast_tanh(bf2f(Etb[eb + c0]) + ptp[c0])
            + acc1[rI]*fast_tanh(bf2f(Etb[eb + c1]) + ptp[c1])
            + acc2[rI]*fast_tanh(bf2f(Etb[eb + c2]) + ptp[c2]);
    s += __shfl_xor(s, 1);  s += __shfl_xor(s, 2);
    s += __shfl_xor(s, 4);  s += __shfl_xor(s, 8);
    s += __shfl_xor(s, 16);
    if ((lane & 31) == 0) redbuf[wr][wc][row] = s;
  }
  __syncthreads();
  if (t < 128){
    atomicAdd(&out[(size_t)(n0 + t)*KK + k],
              redbuf[t>>5][0][t&31] + redbuf[t>>5][1][t&31]);
  }
}

extern "C" void kernel_launch(void* const* d_in, const int* in_sizes, int n_in,
                              void* d_out, int out_size, void* d_ws, size_t ws_size,
                              hipStream_t stream){
  const float* seq      = (const float*)d_in[0];
  const float* att      = (const float*)d_in[1];
  const float* mask     = (const float*)d_in[2];
  const int*   mpos     = (const int*)d_in[3];
  const int*   pairs    = (const int*)d_in[4];
  const float* Wattn    = (const float*)d_in[5];
  const float* battn    = (const float*)d_in[6];
  const float* attn_net = (const float*)d_in[7];
  const float* Wlin     = (const float*)d_in[8];
  const float* blin     = (const float*)d_in[9];
  const float* Wseg     = (const float*)d_in[10];
  const float* bseg     = (const float*)d_in[11];
  const float* Whead    = (const float*)d_in[12];
  const float* bhead    = (const float*)d_in[13];
  const float* Wtail    = (const float*)d_in[14];
  const float* btail    = (const float*)d_in[15];
  const float* bil      = (const float*)d_in[16];
  const float* bilb     = (const float*)d_in[17];
  float* out = (float*)d_out;

  char* ws = (char*)d_ws;
  size_t off = 0;
  auto allocB = [&](size_t nbytes)->char*{
    char* p = ws + off;
    off += (nbytes + 255) & ~(size_t)255;
    return p;
  };
  // ---- persistent (live across the bilinear path) ----
  unsigned short* BF     = (unsigned short*)allocB((size_t)KK*589824*2);    // 114.4 MB
  unsigned short* Ehb    = (unsigned short*)allocB((size_t)MT*32*768*2);    // 25 MB
  unsigned short* Etb    = (unsigned short*)allocB((size_t)MT*32*768*2);    // 25 MB
  unsigned short* WheadF = (unsigned short*)allocB((size_t)589824*2);
  unsigned short* WtailF = (unsigned short*)allocB((size_t)589824*2);
  float* phb  = (float*)allocB((size_t)NPAIR*DD*4);
  float* ptb  = (float*)allocB((size_t)NPAIR*DD*4);
  // ---- union region: {emb,tbuf,wsm,eas,sl,xb,htss,esf} all dead before k_hsts writes hsF ----
  size_t hsF_bytes = (size_t)NT32*KK*48*512*2;                              // 76.3 MB
  char* uni = allocB(hsF_bytes);
  size_t uoff = 0;
  auto ualloc = [&](size_t nbytes)->char*{
    char* p = uni + uoff;
    uoff += (nbytes + 255) & ~(size_t)255;
    return p;
  };
  float* emb  = (float*)ualloc((size_t)BS*NE*NM*DD*4);
  float* tbuf = (float*)ualloc((size_t)BS*NE*NM*RR*4);
  float* wsm  = (float*)ualloc((size_t)BS*NE*NM*KK*4);
  float* eas  = (float*)ualloc((size_t)BS*NE*HH*LL*4);
  float* sl   = (float*)ualloc((size_t)BS*LL*3*4);
  float* xb   = (float*)ualloc((size_t)BS*NE*NE*3*4);
  float* htss = (float*)ualloc((size_t)NPAIR*FF*4);
  unsigned short* esf = (unsigned short*)ualloc((size_t)MT*48*64*8*2);      // 25 MB
  unsigned short* hsF = (unsigned short*)uni;                               // aliases scratch

  k_outinit<<<(NPAIR*KK+255)/256, 256, 0, stream>>>(bilb, out);
  k_emb<<<BS*NE*NM, 256, 0, stream>>>(seq, mpos, mask, emb);
  k_score1<<<BS*NE*NM, 256, 0, stream>>>(emb, Wattn, battn, tbuf);
  k_scores<<<BS*NE, 128, 0, stream>>>(tbuf, attn_net, mask, wsm);
  k_entity_as<<<BS*NE*HH, 256, 0, stream>>>(att, mpos, mask, eas);
  k_entity_es<<<BS*NE, 256, 0, stream>>>(emb, wsm, esf);
  k_seqlin<<<BS*LL, 256, 0, stream>>>(seq, Wlin, sl);
  k_ht_x<<<BS*NE*NE, 256, 0, stream>>>(eas, sl, blin, xb);
  k_conv_pairs<<<NPAIR, 256, 0, stream>>>(xb, pairs, Wseg, bseg, htss);
  k_pair_proj<<<NPAIR, 256, 0, stream>>>(htss, Whead + 768*768, bhead, phb);
  k_pair_proj<<<NPAIR, 256, 0, stream>>>(htss, Wtail + 768*768, btail, ptb);
  k_wshuffle<<<144, 256, 0, stream>>>(Whead, WheadF);
  k_wshuffle<<<144, 256, 0, stream>>>(Wtail, WtailF);
  k_wshuffle<<<KK*144, 256, 0, stream>>>(bil, BF);
  k_gemm_frag2<<<MT*6, 256, 0, stream>>>(esf, WheadF, WtailF, Ehb, Etb);
  k_hsts<<<NT32*KK, 256, 0, stream>>>(Ehb, phb, pairs, hsF);   // esf dead; hsF overwrites union
  k_bil_gemm<<<GRID_BG, 512, 0, stream>>>(hsF, Etb, ptb, BF, pairs, out);
}

// Round 4
// 879.278 us; speedup vs baseline: 1.4143x; 1.0155x over previous
//
#include <hip/hip_runtime.h>
#include <hip/hip_bf16.h>

#define BS 4
#define LL 1024
#define DD 768
#define HH 12
#define NE 42
#define NM 8
#define KK 97
#define PPAIR 128
#define FF 256
#define RR 256
#define NPAIR (BS*PPAIR)     // 512
#define MROWS (BS*NE*KK)     // 16296
#define MT 510               // ceil(16296/32)
#define NT32 16              // 512 pair-rows / 32
#define GRID_BG (8*13*16)    // xcd(8) x kgrp(13) x nt128(4) x ps(4) = 1664

typedef __attribute__((ext_vector_type(8))) short short8;
typedef __attribute__((ext_vector_type(16))) float float16;

__device__ __forceinline__ float fast_tanh(float x){
  x = fminf(fmaxf(x, -15.f), 15.f);
  float e = __expf(2.f*x);
  return 1.f - 2.f/(e + 1.f);
}
__device__ __forceinline__ unsigned short f2bf(float f){
  unsigned int u = __float_as_uint(f);
  unsigned int r = (u + 0x7FFF + ((u>>16)&1)) >> 16;
  return (unsigned short)r;
}
__device__ __forceinline__ float bf2f(unsigned short u){
  return __uint_as_float(((unsigned int)u)<<16);
}
// async global->LDS, 16B per lane; lds base must be wave-uniform
__device__ __forceinline__ void stage16(const void* g, void* l){
  __builtin_amdgcn_global_load_lds(
      (const __attribute__((address_space(1))) void*)g,
      (__attribute__((address_space(3))) void*)l, 16, 0, 0);
}

// ---------------- K1: fused emb + score1 ----------------
// emb[b,e,m,:] = seq[b,pos,:]*mask  (written to global for k_entity_es)
// tbuf[idx,r]  = tanh(emb . Wattn[:,r] + battn[r])
__global__ void k_emb_score1(const float* __restrict__ seq, const int* __restrict__ mpos,
                             const float* __restrict__ mask, const float* __restrict__ Wattn,
                             const float* __restrict__ battn, float* __restrict__ emb,
                             float* __restrict__ tbuf){
  int idx = blockIdx.x;            // (b*NE+e)*NM+m
  int t = threadIdx.x;             // 256 threads, r = t
  int b = idx / (NE*NM);
  float mk = mask[idx];
  int pos = mpos[idx] + 1;
  pos = min(max(pos, 0), LL-1);
  const float* src = seq + ((size_t)b*LL + pos)*DD;
  float* dst = emb + (size_t)idx*DD;
  __shared__ float es[DD];
  float v0 = mk*src[t], v1 = mk*src[t+256], v2 = mk*src[t+512];
  es[t] = v0; es[t+256] = v1; es[t+512] = v2;
  dst[t] = v0; dst[t+256] = v1; dst[t+512] = v2;
  __syncthreads();
  float acc = battn[t];
  for (int dd=0; dd<DD; dd++) acc += es[dd]*Wattn[dd*RR + t];
  tbuf[(size_t)idx*RR + t] = fast_tanh(acc);
}

// ------------- K2: entity_as[b,e,h,l] = sum_m mask*att[b,h,pos,l]/cnt -------------
__global__ void k_entity_as(const float* __restrict__ att, const int* __restrict__ mpos,
                            const float* __restrict__ mask, float* __restrict__ eas){
  int idx = blockIdx.x;            // (b*NE+e)*HH + hh
  int hh = idx % HH; int be = idx / HH;
  int b = be / NE;
  int t = threadIdx.x;
  float cnt = 0.f;
  for (int m=0;m<NM;m++) cnt += mask[be*NM+m];
  float inv = 1.f / fmaxf(cnt, 1.f);
  float acc[4] = {0.f,0.f,0.f,0.f};
  for (int m=0;m<NM;m++){
    float mk = mask[be*NM+m];
    if (mk != 0.f){
      int pos = min(max(mpos[be*NM+m]+1,0), LL-1);
      const float* row = att + (((size_t)b*HH + hh)*LL + pos)*LL;
      acc[0] += mk*row[t]; acc[1] += mk*row[t+256];
      acc[2] += mk*row[t+512]; acc[3] += mk*row[t+768];
    }
  }
  float* dst = eas + (size_t)idx*LL;
  dst[t]=acc[0]*inv; dst[t+256]=acc[1]*inv; dst[t+512]=acc[2]*inv; dst[t+768]=acc[3]*inv;
}

// ------------- K3b: scores + masked softmax over mentions -> w[b,e,m,k] -------------
__global__ void k_scores(const float* __restrict__ tbuf, const float* __restrict__ an,
                         const float* __restrict__ mask, float* __restrict__ w){
  int be = blockIdx.x; int t = threadIdx.x;   // 128 threads
  __shared__ float ts_[NM*RR];                // 8 KB
  __shared__ float an_s[64*98];               // 25 KB chunk of attn_net^T
  for (int i=t; i<NM*RR; i+=128) ts_[i] = tbuf[(size_t)be*NM*RR + i];
  float acc[NM];
  #pragma unroll
  for (int m=0;m<NM;m++) acc[m] = 0.f;
  for (int rc=0; rc<RR; rc+=64){
    __syncthreads();
    for (int i=t; i<KK*64; i+=128){
      int kq = i >> 6, r = i & 63;
      an_s[r*98 + kq] = an[kq*RR + rc + r];
    }
    __syncthreads();
    if (t < KK){
      for (int m=0;m<NM;m++){
        float a = 0.f;
        for (int r=0;r<64;r++) a += ts_[m*RR + rc + r]*an_s[r*98 + t];
        acc[m] += a;
      }
    }
  }
  if (t < KK){
    float s[NM];
    #pragma unroll
    for (int m=0;m<NM;m++){
      float mk = mask[be*NM+m];
      s[m] = acc[m] + (1.f - mk)*(-1e6f);
    }
    float mx = s[0];
    #pragma unroll
    for (int m=1;m<NM;m++) mx = fmaxf(mx, s[m]);
    float sum = 0.f; float e[NM];
    #pragma unroll
    for (int m=0;m<NM;m++){ e[m] = __expf(s[m]-mx); sum += e[m]; }
    float invs = 1.f/sum;
    #pragma unroll
    for (int m=0;m<NM;m++) w[((size_t)be*NM+m)*KK + t] = e[m]*invs;
  }
}

// ------- K4: entity_es -> bf16 in A-fragment order for 32x32x16 MFMA -------
// es_frag[mt][ds][lane][8]: lane = (row&31) + 32*((d>>3)&1), j = d&7, ds = d>>4
__global__ void k_entity_es(const float* __restrict__ emb, const float* __restrict__ w,
                            unsigned short* __restrict__ esf){
  int be = blockIdx.x; int t = threadIdx.x;
  __shared__ float es[NM*DD];    // 24 KB
  __shared__ float ws_[NM*KK];
  for (int i = t; i < NM*DD; i += 256) es[i] = emb[(size_t)be*NM*DD + i];
  for (int i = t; i < NM*KK; i += 256) ws_[i] = w[(size_t)be*NM*KK + i];
  __syncthreads();
  for (int idx = t; idx < KK*96; idx += 256){
    int k = idx % KK, d8 = idx / KK;     // lanes consecutive in k -> broadcast es reads
    int d0 = d8*8;
    float a[8] = {0,0,0,0,0,0,0,0};
    #pragma unroll
    for (int m=0;m<NM;m++){
      float wv = ws_[m*KK + k];
      #pragma unroll
      for (int j=0;j<8;j++) a[j] += wv*es[m*DD + d0 + j];
    }
    int row = be*KK + k;
    int mt = row >> 5, lr = row & 31, ds = d8 >> 1, qq = d8 & 1;
    short8 v;
    #pragma unroll
    for (int j=0;j<8;j++) v[j] = (short)f2bf(a[j]);
    *(short8*)(esf + ((((size_t)mt*48) + ds)*64 + lr + 32*qq)*8) = v;
  }
}

// ------------- K6: seqlin[b,l,c] = seq[b,l,:] . Wlin[:,c]  (shfl reduce) -------------
__global__ void k_seqlin(const float* __restrict__ seq, const float* __restrict__ Wlin,
                         float* __restrict__ sl){
  int bl = blockIdx.x; int t = threadIdx.x;
  int w = t >> 6, lane = t & 63;
  const float* row = seq + (size_t)bl*DD;
  float a0=0.f, a1=0.f, a2=0.f;
  for (int dd=t; dd<DD; dd+=256){
    float v = row[dd];
    a0 += v*Wlin[dd*3+0]; a1 += v*Wlin[dd*3+1]; a2 += v*Wlin[dd*3+2];
  }
  #pragma unroll
  for (int off=1; off<64; off<<=1){
    a0 += __shfl_xor(a0, off); a1 += __shfl_xor(a1, off); a2 += __shfl_xor(a2, off);
  }
  __shared__ float red[4][3];
  if (lane == 0){ red[w][0]=a0; red[w][1]=a1; red[w][2]=a2; }
  __syncthreads();
  if (t < 3) sl[bl*3+t] = red[0][t]+red[1][t]+red[2][t]+red[3][t];
}

// ------------- K5: fused ht einsum + row-normalize + x = htn@seqlin + blin -------------
__global__ void k_ht_x(const float* __restrict__ eas, const float* __restrict__ sl,
                       const float* __restrict__ blin, float* __restrict__ x){
  int idx = blockIdx.x;            // (b*NE+i)*NE + j
  int j = idx % NE; int i = (idx/NE)%NE; int b = idx/(NE*NE);
  int t = threadIdx.x;
  int w = t >> 6, lane = t & 63;
  const float* ai = eas + ((size_t)(b*NE+i))*HH*LL;
  const float* aj = eas + ((size_t)(b*NE+j))*HH*LL;
  float v[4];
  #pragma unroll
  for (int it=0; it<4; it++){
    int l = t + it*256;
    float acc=0.f;
    #pragma unroll
    for (int hh2=0; hh2<HH; hh2++) acc += ai[hh2*LL + l]*aj[hh2*LL + l];
    v[it] = acc * (1.f/HH);
  }
  __shared__ float wsum[4];
  __shared__ float xred[4][3];
  float s = v[0]+v[1]+v[2]+v[3];
  s += __shfl_xor(s, 1);  s += __shfl_xor(s, 2);  s += __shfl_xor(s, 4);
  s += __shfl_xor(s, 8);  s += __shfl_xor(s, 16); s += __shfl_xor(s, 32);
  if (lane == 0) wsum[w] = s;
  __syncthreads();
  float inv = 1.f/((wsum[0]+wsum[1]+wsum[2]+wsum[3]) + 1e-5f);
  float xa[3]={0.f,0.f,0.f};
  #pragma unroll
  for (int it=0; it<4; it++){
    int l = t + it*256;
    float wv = v[it]*inv;
    const float* s3 = sl + ((size_t)b*LL + l)*3;
    xa[0]+=wv*s3[0]; xa[1]+=wv*s3[1]; xa[2]+=wv*s3[2];
  }
  #pragma unroll
  for (int c=0;c<3;c++){
    float q = xa[c];
    q += __shfl_xor(q, 1);  q += __shfl_xor(q, 2);  q += __shfl_xor(q, 4);
    q += __shfl_xor(q, 8);  q += __shfl_xor(q, 16); q += __shfl_xor(q, 32);
    if (lane == 0) xred[w][c] = q;
  }
  __syncthreads();
  if (t < 3) x[(size_t)idx*3 + t] = xred[0][t]+xred[1][t]+xred[2][t]+xred[3][t] + blin[t];
}

// ------------- K8: 3x3x(3->256) conv + relu at gathered pairs -------------
__global__ void k_conv_pairs(const float* __restrict__ x, const int* __restrict__ pairs,
                             const float* __restrict__ Wseg, const float* __restrict__ bseg,
                             float* __restrict__ htss){
  int n = blockIdx.x; int t = threadIdx.x;   // t = f channel
  int b = n / PPAIR;
  int hi = pairs[n*2+0], ti = pairs[n*2+1];
  __shared__ float xs[27];
  if (t < 27){
    int di = t/9, dj = (t/3)%3, ci = t%3;
    int ii = hi + di - 1, jj = ti + dj - 1;
    float v = 0.f;
    if (ii>=0 && ii<NE && jj>=0 && jj<NE) v = x[(((size_t)b*NE+ii)*NE+jj)*3 + ci];
    xs[t] = v;
  }
  __syncthreads();
  float acc = bseg[t];
  #pragma unroll
  for (int tap=0; tap<27; tap++) acc += xs[tap]*Wseg[tap*FF + t];
  htss[(size_t)n*FF + t] = fmaxf(acc, 0.f);
}

// ------------- K9: both pair projections (shared htss staging) -------------
__global__ void k_pair_proj2(const float* __restrict__ htss,
                             const float* __restrict__ Wh, const float* __restrict__ Wt,
                             const float* __restrict__ bh, const float* __restrict__ bt,
                             float* __restrict__ oh, float* __restrict__ ot){
  int n = blockIdx.x; int t = threadIdx.x;
  __shared__ float hs_s[FF];
  hs_s[t] = htss[(size_t)n*FF + t];
  __syncthreads();
  float h0 = bh[t], h1 = bh[t+256], h2 = bh[t+512];
  float t0 = bt[t], t1 = bt[t+256], t2 = bt[t+512];
  for (int r=0;r<FF;r++){
    float hv = hs_s[r];
    const float* wh = Wh + (size_t)r*DD;
    const float* wt = Wt + (size_t)r*DD;
    h0 += hv*wh[t]; h1 += hv*wh[t+256]; h2 += hv*wh[t+512];
    t0 += hv*wt[t]; t1 += hv*wt[t+256]; t2 += hv*wt[t+512];
  }
  float* dh = oh + (size_t)n*DD;
  float* dt = ot + (size_t)n*DD;
  dh[t]=h0; dh[t+256]=h1; dh[t+512]=h2;
  dt[t]=t0; dt[t+256]=t1; dt[t+512]=t2;
}

// ------- K-shuffle: fp32 [768(k)][768(n)] -> bf16 B-frag order -------
// dst[ds(48)][nt(24)][lane(64)][j(8)]: lane = (n&31)+32*((k>>3)&1), j=k&7
__global__ void k_wshuffle(const float* __restrict__ src, unsigned short* __restrict__ dst){
  int bi = blockIdx.x;
  int mat = bi / 144; int r = bi % 144;
  int ds = r / 3, ntg = r % 3;
  int t = threadIdx.x;
  size_t mo = (size_t)mat*589824;
  __shared__ float ls[16][260];
  #pragma unroll
  for (int i=0;i<16;i++)
    ls[i][t] = src[mo + ((size_t)(ds*16+i))*768 + ntg*256 + t];
  __syncthreads();
  #pragma unroll
  for (int it=0; it<2; it++){
    int idx = it*256 + t;           // 0..511
    int pt_l = idx >> 6, lane = idx & 63;
    int nl = pt_l*32 + (lane & 31);
    int qq = lane >> 5;
    short8 v;
    #pragma unroll
    for (int j=0;j<8;j++) v[j] = (short)f2bf(ls[qq*8 + j][nl]);
    *(short8*)(dst + mo + (((size_t)ds*24 + ntg*8 + pt_l)*64 + lane)*8) = v;
  }
}

// ------------- K10: both C_bf16[M,768] = A_frag @ {Bh,Bt} (shared A stream) -------------
__global__ __launch_bounds__(256) void k_gemm_frag2(const unsigned short* __restrict__ Af,
    const unsigned short* __restrict__ Bh, const unsigned short* __restrict__ Bt,
    unsigned short* __restrict__ Ch, unsigned short* __restrict__ Ct){
  int mt = blockIdx.x / 6, ntg = blockIdx.x % 6;
  int t = threadIdx.x; int w = t >> 6; int lane = t & 63;
  int nt = ntg*4 + w;
  float16 acch = (float16)(0.0f), acct = (float16)(0.0f);
  const unsigned short* ap = Af + (((size_t)mt*48)*64 + lane)*8;
  const unsigned short* bph = Bh + (((size_t)nt)*64 + lane)*8;
  const unsigned short* bpt = Bt + (((size_t)nt)*64 + lane)*8;
  #pragma unroll 4
  for (int ds=0; ds<48; ds++){
    short8 a  = *(const short8*)(ap + (size_t)ds*512);
    short8 bh = *(const short8*)(bph + (size_t)ds*24*512);
    short8 bt = *(const short8*)(bpt + (size_t)ds*24*512);
    acch = __builtin_amdgcn_mfma_f32_32x32x16_bf16(a, bh, acch, 0, 0, 0);
    acct = __builtin_amdgcn_mfma_f32_32x32x16_bf16(a, bt, acct, 0, 0, 0);
  }
  int col = nt*32 + (lane & 31);
  int aq = lane >> 5;
  #pragma unroll
  for (int rI=0;rI<16;rI++){
    int row = mt*32 + (rI&3) + 8*(rI>>2) + 4*aq;
    Ch[(size_t)row*768 + col] = f2bf(acch[rI]);
    Ct[(size_t)row*768 + col] = f2bf(acct[rI]);
  }
}

// ------------- K11a: hsF[nt,k,ds,lane,8] = tanh(Ehb[ent(n),k,d] + ph[n,d]) as A-frag bf16 -------------
__global__ void k_hsts(const unsigned short* __restrict__ Ehb, const float* __restrict__ ph,
                       const int* __restrict__ pairs, unsigned short* __restrict__ hsF){
  int bi = blockIdx.x; int nt = bi / KK; int k = bi - nt*KK;
  int t = threadIdx.x;
  __shared__ int ehB[32];
  if (t < 32){
    int n = nt*32 + t; int b = n >> 7;
    ehB[t] = ((b*NE + pairs[n*2+0])*KK + k)*DD;
  }
  __syncthreads();
  unsigned short* dst = hsF + (((size_t)nt*KK + k)*48)*512;
  #pragma unroll 2
  for (int c=0; c<12; c++){
    int L = c*256 + t;
    int ds = L >> 6, lane = L & 63;
    int r = lane & 31, q = lane >> 5;
    int n = nt*32 + r;
    int d0 = ds*16 + q*8;
    short8 ev = *(const short8*)(Ehb + ehB[r] + d0);
    float4 p0 = *(const float4*)(ph + (size_t)n*DD + d0);
    float4 p1 = *(const float4*)(ph + (size_t)n*DD + d0 + 4);
    float pf[8] = {p0.x,p0.y,p0.z,p0.w,p1.x,p1.y,p1.z,p1.w};
    short8 v;
    #pragma unroll
    for (int j=0;j<8;j++) v[j] = (short)f2bf(fast_tanh(bf2f((unsigned short)ev[j]) + pf[j]));
    *(short8*)(dst + (size_t)ds*512 + lane*8) = v;
  }
}

// ------------- K11b: out[n,k] = bias[k] (atomic accumulation target) -------------
__global__ void k_outinit(const float* __restrict__ bias, float* __restrict__ out){
  int i = blockIdx.x*256 + threadIdx.x;
  if (i < NPAIR*KK) out[i] = bias[i % KK];
}

// ------------- K11c: bilinear GEMM, LDS-staged, KSTEP=2 (24 iters, 48 barriers) -------------
// 512 thr = 8 waves: wr=w>>1 (4 row-tiles -> 128 rows), wc=w&1 (p parity).
// Per group (2 ds-steps): 20x 1KB chunks (8 A + 12 B); waves 0-3 stage 3 chunks,
// waves 4-7 stage 2; double-buffered; per-wave counted vmcnt (3/2, never 0 mid-loop).
// XCD-aligned: blockIdx&7 == k%8 -> BF[k] L2-resident.
__global__ __launch_bounds__(512,6) void k_bil_gemm(
    const unsigned short* __restrict__ hsF, const unsigned short* __restrict__ Etb,
    const float* __restrict__ pt_, const unsigned short* __restrict__ Bfrag,
    const int* __restrict__ pairs, float* __restrict__ out){
  int xcd = blockIdx.x & 7; int g = blockIdx.x >> 3;
  int ps = g & 3; int nt = (g >> 2) & 3; int kgrp = g >> 4;
  int k = kgrp*8 + xcd;
  if (k >= KK) return;
  int n0 = nt*128;
  int t = threadIdx.x; int w = t >> 6; int lane = t & 63;
  int wr = w >> 1, wc = w & 1;
  __shared__ int etB[128];
  __shared__ unsigned short ldsAB[2][20][512];   // 40 KB: slots 0-7 = A(ds2*4+mt), 8-19 = B(8+ds2*6+p)
  __shared__ float redbuf[4][2][32];
  if (t < 128){
    int n = n0 + t; int b = n >> 7;
    etB[t] = ((b*NE + pairs[n*2+1])*KK + k)*DD;
  }
  __syncthreads();
  int aq = lane >> 5;
  // chunk 0 (all waves): A, ds2 = w>>2, mt_loc = w&3
  const unsigned short* g0 = hsF + ((((size_t)(nt*4 + (w&3))*KK + k)*48) + (w>>2))*512 + (size_t)lane*8;
  // chunk 1 (all waves): B, cb = w -> ds2 = w/6, p = w%6
  int d21 = w/6, p1 = w - d21*6;
  const unsigned short* g1 = Bfrag + (size_t)k*589824
                           + ((size_t)(d21*24 + ps*6 + p1))*512 + (size_t)lane*8;
  // chunk 2 (w<4): B, cb = w+8 -> ds2 = 1, p = w+2
  const unsigned short* g2 = Bfrag + (size_t)k*589824
                           + ((size_t)(1*24 + ps*6 + (w+2)))*512 + (size_t)lane*8;
  float16 acc0 = (float16)(0.f), acc1 = (float16)(0.f), acc2 = (float16)(0.f);
  // prologue: stage group 0 into buf 0
  {
    stage16(g0, &ldsAB[0][w][0]);
    stage16(g1, &ldsAB[0][8+w][0]);
    if (w < 4) stage16(g2, &ldsAB[0][16+w][0]);
  }
  for (int it=0; it<24; ++it){
    int buf = it & 1;
    if (it < 23){
      stage16(g0 + (size_t)(it+1)*1024,  &ldsAB[buf^1][w][0]);
      stage16(g1 + (size_t)(it+1)*24576, &ldsAB[buf^1][8+w][0]);
      if (w < 4){
        stage16(g2 + (size_t)(it+1)*24576, &ldsAB[buf^1][16+w][0]);
        asm volatile("s_waitcnt vmcnt(3)" ::: "memory");
      } else {
        asm volatile("s_waitcnt vmcnt(2)" ::: "memory");
      }
    } else {
      asm volatile("s_waitcnt vmcnt(0)" ::: "memory");
    }
    asm volatile("s_barrier" ::: "memory");
    #pragma unroll
    for (int d2=0; d2<2; ++d2){
      short8 a  = *(const short8*)&ldsAB[buf][d2*4+wr][lane*8];
      short8 b0 = *(const short8*)&ldsAB[buf][8+d2*6+wc  ][lane*8];
      short8 b1 = *(const short8*)&ldsAB[buf][8+d2*6+wc+2][lane*8];
      short8 b2 = *(const short8*)&ldsAB[buf][8+d2*6+wc+4][lane*8];
      acc0 = __builtin_amdgcn_mfma_f32_32x32x16_bf16(a, b0, acc0, 0, 0, 0);
      acc1 = __builtin_amdgcn_mfma_f32_32x32x16_bf16(a, b1, acc1, 0, 0, 0);
      acc2 = __builtin_amdgcn_mfma_f32_32x32x16_bf16(a, b2, acc2, 0, 0, 0);
    }
    asm volatile("s_barrier" ::: "memory");
  }
  int pb0 = ps*6 + wc;                 // tiles pb0, pb0+2, pb0+4
  // epilogue: s = sum over this wave's 3 p-tiles of U[row,p]*tanh(Et+pt)[row,p]
  #pragma unroll
  for (int rI=0; rI<16; rI++){
    int row = (rI&3) + 8*(rI>>2) + 4*aq;   // 0..31 within wave's row-tile
    int nloc = wr*32 + row;
    int eb = etB[nloc];
    const float* ptp = pt_ + (size_t)(n0 + nloc)*DD;
    int colb = lane & 31;
    int c0 = (pb0+0)*32 + colb, c1 = (pb0+2)*32 + colb, c2 = (pb0+4)*32 + colb;
    float s = acc0[rI]*fast_tanh(bf2f(Etb[eb + c0]) + ptp[c0])
            + acc1[rI]*fast_tanh(bf2f(Etb[eb + c1]) + ptp[c1])
            + acc2[rI]*fast_tanh(bf2f(Etb[eb + c2]) + ptp[c2]);
    s += __shfl_xor(s, 1);  s += __shfl_xor(s, 2);
    s += __shfl_xor(s, 4);  s += __shfl_xor(s, 8);
    s += __shfl_xor(s, 16);
    if ((lane & 31) == 0) redbuf[wr][wc][row] = s;
  }
  __syncthreads();
  if (t < 128){
    atomicAdd(&out[(size_t)(n0 + t)*KK + k],
              redbuf[t>>5][0][t&31] + redbuf[t>>5][1][t&31]);
  }
}

extern "C" void kernel_launch(void* const* d_in, const int* in_sizes, int n_in,
                              void* d_out, int out_size, void* d_ws, size_t ws_size,
                              hipStream_t stream){
  const float* seq      = (const float*)d_in[0];
  const float* att      = (const float*)d_in[1];
  const float* mask     = (const float*)d_in[2];
  const int*   mpos     = (const int*)d_in[3];
  const int*   pairs    = (const int*)d_in[4];
  const float* Wattn    = (const float*)d_in[5];
  const float* battn    = (const float*)d_in[6];
  const float* attn_net = (const float*)d_in[7];
  const float* Wlin     = (const float*)d_in[8];
  const float* blin     = (const float*)d_in[9];
  const float* Wseg     = (const float*)d_in[10];
  const float* bseg     = (const float*)d_in[11];
  const float* Whead    = (const float*)d_in[12];
  const float* bhead    = (const float*)d_in[13];
  const float* Wtail    = (const float*)d_in[14];
  const float* btail    = (const float*)d_in[15];
  const float* bil      = (const float*)d_in[16];
  const float* bilb     = (const float*)d_in[17];
  float* out = (float*)d_out;

  char* ws = (char*)d_ws;
  size_t off = 0;
  auto allocB = [&](size_t nbytes)->char*{
    char* p = ws + off;
    off += (nbytes + 255) & ~(size_t)255;
    return p;
  };
  // ---- persistent (live across the bilinear path) ----
  unsigned short* BF     = (unsigned short*)allocB((size_t)KK*589824*2);    // 114.4 MB
  unsigned short* Ehb    = (unsigned short*)allocB((size_t)MT*32*768*2);    // 25 MB
  unsigned short* Etb    = (unsigned short*)allocB((size_t)MT*32*768*2);    // 25 MB
  unsigned short* WheadF = (unsigned short*)allocB((size_t)589824*2);
  unsigned short* WtailF = (unsigned short*)allocB((size_t)589824*2);
  float* phb  = (float*)allocB((size_t)NPAIR*DD*4);
  float* ptb  = (float*)allocB((size_t)NPAIR*DD*4);
  // ---- union region: {emb,tbuf,wsm,eas,sl,xb,htss,esf} all dead before k_hsts writes hsF ----
  size_t hsF_bytes = (size_t)NT32*KK*48*512*2;                              // 76.3 MB
  char* uni = allocB(hsF_bytes);
  size_t uoff = 0;
  auto ualloc = [&](size_t nbytes)->char*{
    char* p = uni + uoff;
    uoff += (nbytes + 255) & ~(size_t)255;
    return p;
  };
  float* emb  = (float*)ualloc((size_t)BS*NE*NM*DD*4);
  float* tbuf = (float*)ualloc((size_t)BS*NE*NM*RR*4);
  float* wsm  = (float*)ualloc((size_t)BS*NE*NM*KK*4);
  float* eas  = (float*)ualloc((size_t)BS*NE*HH*LL*4);
  float* sl   = (float*)ualloc((size_t)BS*LL*3*4);
  float* xb   = (float*)ualloc((size_t)BS*NE*NE*3*4);
  float* htss = (float*)ualloc((size_t)NPAIR*FF*4);
  unsigned short* esf = (unsigned short*)ualloc((size_t)MT*48*64*8*2);      // 25 MB
  unsigned short* hsF = (unsigned short*)uni;                               // aliases scratch

  k_outinit<<<(NPAIR*KK+255)/256, 256, 0, stream>>>(bilb, out);
  k_emb_score1<<<BS*NE*NM, 256, 0, stream>>>(seq, mpos, mask, Wattn, battn, emb, tbuf);
  k_scores<<<BS*NE, 128, 0, stream>>>(tbuf, attn_net, mask, wsm);
  k_entity_as<<<BS*NE*HH, 256, 0, stream>>>(att, mpos, mask, eas);
  k_entity_es<<<BS*NE, 256, 0, stream>>>(emb, wsm, esf);
  k_seqlin<<<BS*LL, 256, 0, stream>>>(seq, Wlin, sl);
  k_ht_x<<<BS*NE*NE, 256, 0, stream>>>(eas, sl, blin, xb);
  k_conv_pairs<<<NPAIR, 256, 0, stream>>>(xb, pairs, Wseg, bseg, htss);
  k_pair_proj2<<<NPAIR, 256, 0, stream>>>(htss, Whead + 768*768, Wtail + 768*768,
                                          bhead, btail, phb, ptb);
  k_wshuffle<<<144, 256, 0, stream>>>(Whead, WheadF);
  k_wshuffle<<<144, 256, 0, stream>>>(Wtail, WtailF);
  k_wshuffle<<<KK*144, 256, 0, stream>>>(bil, BF);
  k_gemm_frag2<<<MT*6, 256, 0, stream>>>(esf, WheadF, WtailF, Ehb, Etb);
  k_hsts<<<NT32*KK, 256, 0, stream>>>(Ehb, phb, pairs, hsF);   // esf dead; hsF overwrites union
  k_bil_gemm<<<GRID_BG, 512, 0, stream>>>(hsF, Etb, ptb, BF, pairs, out);
}